// Round 1
// 2223.126 us; speedup vs baseline: 1.4645x; 1.4645x over previous
//
#include <hip/hip_runtime.h>
#include <math.h>

#define NB 16384
#define DIN 768

typedef _Float16 f16x8 __attribute__((ext_vector_type(8)));
typedef float f32x16 __attribute__((ext_vector_type(16)));

// ---------------- small kernels ----------------

__global__ void k_zero2(float* a, float* b) {
    if (threadIdx.x == 0) { *a = 0.f; *b = 0.f; }
}

__global__ void k_norm(const float* __restrict__ x, const float* __restrict__ m,
                       const float* __restrict__ s, float* __restrict__ xn) {
    int i = blockIdx.x * 256 + threadIdx.x;          // 16384*768 total
    int j = i % DIN;
    xn[i] = (x[i] - m[j]) / s[j];
}

// one 64-lane wave per codebook row (4 rows / 256-thread block)
// NOTE: writes ||E||^2 * 4096 (the r*16, E*256 scaling used by the fp16-split
// argmin; argmin is invariant under this uniform scale)
__global__ void k_cbnorm(const float* __restrict__ cb, float* __restrict__ cbn) {
    int row = blockIdx.x * 4 + (threadIdx.x >> 6);
    int lane = threadIdx.x & 63;
    const float* p = cb + (size_t)row * 128;
    float v0 = p[lane], v1 = p[lane + 64];
    float s = v0 * v0 + v1 * v1;
    #pragma unroll
    for (int m = 32; m >= 1; m >>= 1) s += __shfl_xor(s, m, 64);
    if (lane == 0) cbn[row] = s * 4096.f;
}

// split fp32 rows (n x 128) into fp16 hi|lo layout (n x 256): [hi(128) | lo(128)]
__global__ void k_split(const float* __restrict__ src, _Float16* __restrict__ dst,
                        float scale) {
    int i = blockIdx.x * 256 + threadIdx.x;   // n*128 elements
    int row = i >> 7, d = i & 127;
    float v = src[i] * scale;
    _Float16 hi = (_Float16)v;
    dst[(size_t)row * 256 + d] = hi;
    dst[(size_t)row * 256 + 128 + d] = (_Float16)(v - (float)hi);
}

// ---------------- fused Linear + ReLU + RMSNorm ----------------
// block = 32 rows x N cols; threads (tx=32, ty=8); per-thread 4 rows x N/32 cols
template <int N>
__global__ __launch_bounds__(256, 2) void k_lin_relu_rms(
    const float* __restrict__ A, const float* __restrict__ W,
    const float* __restrict__ bias, const float* __restrict__ g,
    float* __restrict__ out, int K) {
    constexpr int CJ = N / 32;
    __shared__ float Asub[32][17];
    __shared__ float Wsub[16][N];
    __shared__ float rsums[32];
    const int tid = threadIdx.x;
    const int tx = tid & 31, ty = tid >> 5;
    const int row0 = blockIdx.x * 32;

    float acc[4][CJ];
    #pragma unroll
    for (int r = 0; r < 4; r++)
        #pragma unroll
        for (int j = 0; j < CJ; j++) acc[r][j] = 0.f;

    for (int k0 = 0; k0 < K; k0 += 16) {
        for (int e = tid; e < 512; e += 256) {
            int r = e >> 4, kk = e & 15;
            Asub[r][kk] = A[(size_t)(row0 + r) * K + k0 + kk];
        }
        constexpr int NW4 = 16 * N / 4;
        for (int e = tid; e < NW4; e += 256) {
            int kk = e / (N / 4), c4 = e % (N / 4);
            *(float4*)&Wsub[kk][c4 * 4] = *(const float4*)&W[(size_t)(k0 + kk) * N + c4 * 4];
        }
        __syncthreads();
        #pragma unroll
        for (int kk = 0; kk < 16; kk++) {
            float a[4];
            #pragma unroll
            for (int r = 0; r < 4; r++) a[r] = Asub[ty * 4 + r][kk];
            #pragma unroll
            for (int j = 0; j < CJ; j++) {
                float w = Wsub[kk][tx + 32 * j];
                #pragma unroll
                for (int r = 0; r < 4; r++) acc[r][j] = fmaf(a[r], w, acc[r][j]);
            }
        }
        __syncthreads();
    }
    // bias + relu + per-row sum of squares
    float ss[4] = {0.f, 0.f, 0.f, 0.f};
    #pragma unroll
    for (int j = 0; j < CJ; j++) {
        float bb = bias[tx + 32 * j];
        #pragma unroll
        for (int r = 0; r < 4; r++) {
            float v = acc[r][j] + bb;
            v = v > 0.f ? v : 0.f;
            acc[r][j] = v;
            ss[r] = fmaf(v, v, ss[r]);
        }
    }
    #pragma unroll
    for (int m = 1; m < 32; m <<= 1)
        #pragma unroll
        for (int r = 0; r < 4; r++) ss[r] += __shfl_xor(ss[r], m, 64);
    if (tx == 0)
        #pragma unroll
        for (int r = 0; r < 4; r++) rsums[ty * 4 + r] = ss[r];
    __syncthreads();
    constexpr float invN = 1.0f / (float)N;
    #pragma unroll
    for (int r = 0; r < 4; r++) {
        float scale = 1.0f / sqrtf(rsums[ty * 4 + r] * invN + 1e-6f);
        #pragma unroll
        for (int j = 0; j < CJ; j++) {
            int col = tx + 32 * j;
            out[(size_t)(row0 + ty * 4 + r) * N + col] = acc[r][j] * scale * g[col];
        }
    }
}

// ---------------- VQ: fp16 hi/lo split MFMA scores + partial argmin ----------------
// score s_c = 4096*||E_c||^2 - 2*(16 r)·(256 E_c)
// dot computed with 3 MFMA products: hi*hi + hi*lo + lo*hi  (error ~2^-22 rel)
// grid (NB/128, 2 strips of 4096 codes); block 512 = 8 waves.
// wave w: wr=w>>1 -> rows [row0+wr*32, +32); wc=w&1 -> 32-code half of each 64-chunk.
// A (32 rows x 256 split-halfs) lives in registers (64 VGPR), loaded once.
// E chunk (64 codes x 256 halfs = 32KB) double-buffered in LDS, XOR-swizzled
// (slot ^ (code&31)) so the stride-512B ds_read_b128 is bank-conflict-free.
// Three independent accumulator chains cover MFMA latency at 2 waves/SIMD.
__global__ __launch_bounds__(512, 2) void k_vq_argmin_mfma(
    const _Float16* __restrict__ Rsp, const _Float16* __restrict__ Esp,
    const float* __restrict__ cbnS,
    float* __restrict__ pbest, int* __restrict__ pidx) {
    __shared__ __align__(16) _Float16 Es[2][64 * 256];
    const int tid = threadIdx.x;
    const int w = tid >> 6, lane = tid & 63;
    const int wr = w >> 1, wc = w & 1;
    const int g = lane >> 5, cl31 = lane & 31;
    const int row0 = blockIdx.x * 128 + wr * 32;
    const int cbase = blockIdx.y * 4096;

    // A fragments: row = row0 + (lane&31), k-group g = lane>>5 (8 halfs each)
    f16x8 Ah[8], Al[8];
    {
        const _Float16* rp = Rsp + (size_t)(row0 + cl31) * 256 + g * 8;
        #pragma unroll
        for (int kc = 0; kc < 8; kc++) {
            Ah[kc] = *(const f16x8*)(rp + kc * 16);
            Al[kc] = *(const f16x8*)(rp + 128 + kc * 16);
        }
    }

    float best[16];
    int bidx[16];
    #pragma unroll
    for (int m = 0; m < 16; m++) { best[m] = 3.402823466e+38f; bidx[m] = 0; }

    // stage chunk 0 (all 512 threads: 64 codes x 512B, 4 x float4 each)
    float4 st[4];
    #pragma unroll
    for (int p = 0; p < 4; p++) {
        int f = tid + 512 * p;
        int c = f >> 5, sl = f & 31;
        st[p] = *(const float4*)(Esp + (size_t)(cbase + c) * 256 + sl * 8);
    }
    #pragma unroll
    for (int p = 0; p < 4; p++) {
        int f = tid + 512 * p;
        int c = f >> 5, sl = f & 31;
        *(float4*)&Es[0][c * 256 + ((sl ^ (c & 31)) * 8)] = st[p];
    }
    __syncthreads();

    const int cloc = wc * 32 + cl31;          // code row within the 64-chunk
    const int swz = cloc & 31;

    for (int ch = 0; ch < 64; ch++) {
        const int buf = ch & 1;
        // prefetch next chunk into regs (latency hidden under the MFMAs)
        if (ch < 63) {
            #pragma unroll
            for (int p = 0; p < 4; p++) {
                int f = tid + 512 * p;
                int c = f >> 5, sl = f & 31;
                st[p] = *(const float4*)(Esp + (size_t)(cbase + (ch + 1) * 64 + c) * 256 + sl * 8);
            }
        }
        // 3 independent accumulation chains (hi*hi, lo*hi, hi*lo)
        f32x16 a0, a1, a2;
        #pragma unroll
        for (int m = 0; m < 16; m++) { a0[m] = 0.f; a1[m] = 0.f; a2[m] = 0.f; }
        #pragma unroll
        for (int kc = 0; kc < 8; kc++) {
            int sh = kc * 2 + g;
            f16x8 bh = *(const f16x8*)&Es[buf][cloc * 256 + ((sh ^ swz) * 8)];
            f16x8 bl = *(const f16x8*)&Es[buf][cloc * 256 + (((sh + 16) ^ swz) * 8)];
            a0 = __builtin_amdgcn_mfma_f32_32x32x16_f16(Ah[kc], bh, a0, 0, 0, 0);
            a1 = __builtin_amdgcn_mfma_f32_32x32x16_f16(Al[kc], bh, a1, 0, 0, 0);
            a2 = __builtin_amdgcn_mfma_f32_32x32x16_f16(Ah[kc], bl, a2, 0, 0, 0);
        }
        // running argmin; codes visited in ascending order -> strict < keeps first
        int c = cbase + ch * 64 + cloc;
        float cn = cbnS[c];
        #pragma unroll
        for (int m = 0; m < 16; m++) {
            float s = fmaf(-2.f, a0[m] + a1[m] + a2[m], cn);
            if (s < best[m]) { best[m] = s; bidx[m] = c; }
        }
        if (ch < 63) {
            __syncthreads();   // everyone done reading buf^1 (chunk ch-1)
            #pragma unroll
            for (int p = 0; p < 4; p++) {
                int f = tid + 512 * p;
                int cc = f >> 5, sl = f & 31;
                *(float4*)&Es[buf ^ 1][cc * 256 + ((sl ^ (cc & 31)) * 8)] = st[p];
            }
            __syncthreads();
        }
    }

    // reduce across 32 code-lanes (xor masks < 32 stay within the lane-half);
    // tie -> smaller index (numpy first-occurrence)
    #pragma unroll
    for (int mask = 1; mask < 32; mask <<= 1) {
        #pragma unroll
        for (int m = 0; m < 16; m++) {
            float ob = __shfl_xor(best[m], mask, 64);
            int oi = __shfl_xor(bidx[m], mask, 64);
            if (ob < best[m] || (ob == best[m] && oi < bidx[m])) { best[m] = ob; bidx[m] = oi; }
        }
    }
    if (cl31 == 0) {
        int part = blockIdx.y * 2 + wc;
        // C/D layout (m74): row = (reg&3) + 8*(reg>>2) + 4*(lane>>5)
        #pragma unroll
        for (int m = 0; m < 16; m++) {
            int row = row0 + (m & 3) + 8 * (m >> 2) + 4 * g;
            pbest[(size_t)part * NB + row] = best[m];
            pidx[(size_t)part * NB + row] = bidx[m];
        }
    }
}

// merge the 4 partials (2 strips x 2 wave-halves); tie -> smaller index
__global__ void k_vq_reduce(const float* __restrict__ pbest, const int* __restrict__ pidx,
                            int* __restrict__ idx_out, float* __restrict__ ids_f) {
    int row = blockIdx.x * 256 + threadIdx.x;
    float b = pbest[row];
    int bi = pidx[row];
    #pragma unroll
    for (int s = 1; s < 4; s++) {
        float ob = pbest[(size_t)s * NB + row];
        int oi = pidx[(size_t)s * NB + row];
        if (ob < b || (ob == b && oi < bi)) { b = ob; bi = oi; }
    }
    idx_out[row] = bi;
    ids_f[(size_t)row * 4] = (float)bi;
}

// gather + residual update + qsum + vq_loss partial; also writes fp16 hi/lo
// split of the new residual (scale 16) for the next quantizer's argmin
__global__ void k_vq_update(const float* __restrict__ Rin, const int* __restrict__ idx,
                            const float* __restrict__ E, float* __restrict__ Rout,
                            float* __restrict__ qsum, float* __restrict__ vq_acc,
                            int firstq, _Float16* __restrict__ Rsp) {
    __shared__ float ps[4];
    int i = blockIdx.x * 256 + threadIdx.x;   // NB*128 total
    int row = i >> 7, d = i & 127;
    float e = E[(size_t)idx[row] * 128 + d];
    float rv = Rin[i] - e;
    Rout[i] = rv;
    qsum[i] = firstq ? e : (qsum[i] + e);
    float rs = rv * 16.f;
    _Float16 hi = (_Float16)rs;
    Rsp[(size_t)row * 256 + d] = hi;
    Rsp[(size_t)row * 256 + 128 + d] = (_Float16)(rs - (float)hi);
    float p = rv * rv;
    #pragma unroll
    for (int m = 1; m < 64; m <<= 1) p += __shfl_xor(p, m, 64);
    int lane = threadIdx.x & 63, w = threadIdx.x >> 6;
    if (lane == 0) ps[w] = p;
    __syncthreads();
    if (threadIdx.x == 0)
        atomicAdd(vq_acc, (ps[0] + ps[1] + ps[2] + ps[3]) * (1.25f / ((float)NB * 128.f)));
}

// ---------------- final Linear (512->768) + recon loss ----------------
// 64x64 tile; threads (16,16); micro 4x4. Reads xn from rec[], overwrites with recon.
__global__ __launch_bounds__(256, 2) void k_dec2(
    const float* __restrict__ A, const float* __restrict__ W,
    const float* __restrict__ bias, float* __restrict__ rec,
    float* __restrict__ loss_acc) {
    __shared__ float Asub[64][17];
    __shared__ float Wsub[16][64];
    __shared__ float red[4];
    const int tid = threadIdx.x;
    const int tx = tid & 15, ty = tid >> 4;
    const int row0 = blockIdx.x * 64, col0 = blockIdx.y * 64;
    float acc[4][4];
    #pragma unroll
    for (int r = 0; r < 4; r++)
        #pragma unroll
        for (int j = 0; j < 4; j++) acc[r][j] = 0.f;

    for (int k0 = 0; k0 < 512; k0 += 16) {
        for (int e = tid; e < 1024; e += 256) {
            int r = e >> 4, kk = e & 15;
            Asub[r][kk] = A[(size_t)(row0 + r) * 512 + k0 + kk];
        }
        {
            int kk = tid >> 4, c = tid & 15;
            *(float4*)&Wsub[kk][c * 4] = *(const float4*)&W[(size_t)(k0 + kk) * DIN + col0 + c * 4];
        }
        __syncthreads();
        #pragma unroll
        for (int kk = 0; kk < 16; kk++) {
            float a[4], wv[4];
            #pragma unroll
            for (int r = 0; r < 4; r++) a[r] = Asub[ty * 4 + r][kk];
            #pragma unroll
            for (int j = 0; j < 4; j++) wv[j] = Wsub[kk][tx + 16 * j];
            #pragma unroll
            for (int r = 0; r < 4; r++)
                #pragma unroll
                for (int j = 0; j < 4; j++) acc[r][j] = fmaf(a[r], wv[j], acc[r][j]);
        }
        __syncthreads();
    }
    float lsum = 0.f;
    #pragma unroll
    for (int j = 0; j < 4; j++) {
        int col = col0 + tx + 16 * j;
        float bb = bias[col];
        #pragma unroll
        for (int r = 0; r < 4; r++) {
            int row = row0 + ty * 4 + r;
            float v = acc[r][j] + bb;
            size_t o = (size_t)row * DIN + col;
            float e = v - rec[o];     // rec holds xn here
            lsum = fmaf(e, e, lsum);
            rec[o] = v;
        }
    }
    #pragma unroll
    for (int m = 1; m < 64; m <<= 1) lsum += __shfl_xor(lsum, m, 64);
    int lane = tid & 63, w = tid >> 6;
    if (lane == 0) red[w] = lsum;
    __syncthreads();
    if (tid == 0)
        atomicAdd(loss_acc, (red[0] + red[1] + red[2] + red[3]) * (1.0f / ((float)NB * (float)DIN)));
}

// ---------------- launch ----------------

extern "C" void kernel_launch(void* const* d_in, const int* in_sizes, int n_in,
                              void* d_out, int out_size, void* d_ws, size_t ws_size,
                              hipStream_t stream) {
    (void)in_sizes; (void)n_in; (void)out_size; (void)ws_size;
    const float* x        = (const float*)d_in[0];
    const float* emb_mean = (const float*)d_in[1];
    const float* emb_std  = (const float*)d_in[2];
    const float* enc_w0 = (const float*)d_in[3];
    const float* enc_b0 = (const float*)d_in[4];
    const float* enc_g0 = (const float*)d_in[5];
    const float* enc_w1 = (const float*)d_in[6];
    const float* enc_b1 = (const float*)d_in[7];
    const float* enc_g1 = (const float*)d_in[8];
    const float* enc_w2 = (const float*)d_in[9];
    const float* enc_b2 = (const float*)d_in[10];
    const float* enc_g2 = (const float*)d_in[11];
    const float* cb     = (const float*)d_in[12];
    const float* dec_w0 = (const float*)d_in[13];
    const float* dec_b0 = (const float*)d_in[14];
    const float* dec_g0 = (const float*)d_in[15];
    const float* dec_w1 = (const float*)d_in[16];
    const float* dec_b1 = (const float*)d_in[17];
    const float* dec_g1 = (const float*)d_in[18];
    const float* dec_w2 = (const float*)d_in[19];
    const float* dec_b2 = (const float*)d_in[20];

    float* out   = (float*)d_out;
    float* xn    = out;                        // recon region doubles as xn scratch
    float* ids_f = out + (size_t)NB * DIN;     // 12582912
    float* rl    = out + (size_t)NB * DIN + (size_t)NB * 4;      // 12648448
    float* vl    = rl + 1;

    float* ws   = (float*)d_ws;
    float* h0   = ws;                           // 16384*512
    float* h1   = h0 + (size_t)NB * 512;        // 16384*256
    float* h2   = h1 + (size_t)NB * 256;        // 16384*128
    float* rbuf = h2 + (size_t)NB * 128;        // 16384*128
    float* qsum = rbuf + (size_t)NB * 128;      // 16384*128
    float* cbn  = qsum + (size_t)NB * 128;      // 4*8192
    int*   idxb = (int*)(cbn + 4 * 8192);       // 16384

    // h0 is free between encoder stage 1 and decoder stage 1 -> VQ scratch:
    //   pbest: 4*NB floats, pidx: 4*NB ints,
    //   Rsplit: NB*256 halfs (= NB*128 float-equiv),
    //   Esplit: 4*8192*256 halfs (= NB*256 float-equiv). Total 6.42M floats < 8.39M.
    float*    pbest = h0;                                   // 4*16384
    int*      pidx  = (int*)(h0 + 4 * (size_t)NB);          // 4*16384
    _Float16* Rsp   = (_Float16*)(h0 + 8 * (size_t)NB);
    _Float16* Esp   = (_Float16*)(h0 + 8 * (size_t)NB + (size_t)NB * 128);

    k_zero2<<<1, 64, 0, stream>>>(rl, vl);
    k_norm<<<(NB * DIN) / 256, 256, 0, stream>>>(x, emb_mean, emb_std, xn);
    k_cbnorm<<<(4 * 8192) / 4, 256, 0, stream>>>(cb, cbn);

    k_lin_relu_rms<512><<<NB / 32, 256, 0, stream>>>(xn, enc_w0, enc_b0, enc_g0, h0, 768);
    k_lin_relu_rms<256><<<NB / 32, 256, 0, stream>>>(h0, enc_w1, enc_b1, enc_g1, h1, 512);
    k_lin_relu_rms<128><<<NB / 32, 256, 0, stream>>>(h1, enc_w2, enc_b2, enc_g2, h2, 256);

    // fp16 hi/lo splits (after enc1 consumed h0): E*256 (all 4 codebooks), r*16
    k_split<<<(4 * 8192 * 128) / 256, 256, 0, stream>>>(cb, Esp, 256.f);
    k_split<<<(NB * 128) / 256, 256, 0, stream>>>(h2, Rsp, 16.f);

    for (int q = 0; q < 4; q++) {
        const float* R = (q == 0) ? h2 : rbuf;
        const float* Eq = cb + (size_t)q * 8192 * 128;
        const _Float16* EspQ = Esp + (size_t)q * 8192 * 256;
        dim3 gq(NB / 128, 2);
        k_vq_argmin_mfma<<<gq, 512, 0, stream>>>(Rsp, EspQ, cbn + q * 8192, pbest, pidx);
        k_vq_reduce<<<NB / 256, 256, 0, stream>>>(pbest, pidx, idxb, ids_f + q);
        k_vq_update<<<(NB * 128) / 256, 256, 0, stream>>>(R, idxb, Eq, rbuf, qsum, vl,
                                                          q == 0 ? 1 : 0, Rsp);
    }

    k_lin_relu_rms<256><<<NB / 32, 256, 0, stream>>>(qsum, dec_w0, dec_b0, dec_g0, h1, 128);
    k_lin_relu_rms<512><<<NB / 32, 256, 0, stream>>>(h1, dec_w1, dec_b1, dec_g1, h0, 256);

    dim3 g2(NB / 64, DIN / 64);
    k_dec2<<<g2, 256, 0, stream>>>(h0, dec_w2, dec_b2, xn, rl);
}

// Round 2
// 1614.630 us; speedup vs baseline: 2.0164x; 1.3769x over previous
//
#include <hip/hip_runtime.h>
#include <math.h>

#define NB 16384
#define DIN 768

typedef _Float16 f16x8 __attribute__((ext_vector_type(8)));
typedef float f32x16 __attribute__((ext_vector_type(16)));

// ---------------- small kernels ----------------

__global__ void k_zero2(float* a, float* b) {
    if (threadIdx.x == 0) { *a = 0.f; *b = 0.f; }
}

__global__ void k_norm(const float* __restrict__ x, const float* __restrict__ m,
                       const float* __restrict__ s, float* __restrict__ xn) {
    int i = blockIdx.x * 256 + threadIdx.x;          // 16384*768 total
    int j = i % DIN;
    xn[i] = (x[i] - m[j]) / s[j];
}

// one 64-lane wave per codebook row; writes ||E||^2 * 4096 (r*16, E*256 scaling)
__global__ void k_cbnorm(const float* __restrict__ cb, float* __restrict__ cbn) {
    int row = blockIdx.x * 4 + (threadIdx.x >> 6);
    int lane = threadIdx.x & 63;
    const float* p = cb + (size_t)row * 128;
    float v0 = p[lane], v1 = p[lane + 64];
    float s = v0 * v0 + v1 * v1;
    #pragma unroll
    for (int m = 32; m >= 1; m >>= 1) s += __shfl_xor(s, m, 64);
    if (lane == 0) cbn[row] = s * 4096.f;
}

// split fp32 rows (n x 128) into fp16 hi|lo layout (n x 256): [hi(128) | lo(128)]
__global__ void k_split(const float* __restrict__ src, _Float16* __restrict__ dst,
                        float scale) {
    int i = blockIdx.x * 256 + threadIdx.x;   // n*128 elements
    int row = i >> 7, d = i & 127;
    float v = src[i] * scale;
    _Float16 hi = (_Float16)v;
    dst[(size_t)row * 256 + d] = hi;
    dst[(size_t)row * 256 + 128 + d] = (_Float16)(v - (float)hi);
}

// ---------------- weight transpose-split into chunked granule layout ----------
// W (K x N fp32) -> Wt halfs, granule (kc, s, c): ((kc*8+s)*N + c)*8 + j
// k = kc*32 + t*16 + g*8 + j ; s = t*2+g (hi), 4+t*2+g (lo). Scale 256.
__global__ void k_wsplit(const float* __restrict__ W, _Float16* __restrict__ Wt,
                         int K, int N) {
    int i = blockIdx.x * 256 + threadIdx.x;   // K*N total
    int k = i / N, c = i - k * N;
    float v = W[i] * 256.f;
    _Float16 hi = (_Float16)v;
    _Float16 lo = (_Float16)(v - (float)hi);
    int kc = k >> 5, kin = k & 31;
    int t = kin >> 4, gg = (kin >> 3) & 1, j = kin & 7;
    size_t base = ((size_t)(kc * 8) * N + c) * 8 + j;
    Wt[base + (size_t)(t * 2 + gg) * N * 8] = hi;
    Wt[base + (size_t)(4 + t * 2 + gg) * N * 8] = lo;
}

// ---------------- fused MFMA Linear + ReLU + RMSNorm ----------------
// block = 64 rows x N cols, 512 thr = 8 waves (2 row-groups x 4 col-groups).
// A fp32 (M x K) converted to hi/lo fp16 in-register (scale 16); Wt pre-split
// chunked (scale 256). K-chunks of 32, LDS double-buffered via
// global_load_lds width 16 (1 barrier per chunk). 3 MFMA products per tile
// (hi*hi + lo*hi + hi*lo) chained into one f32 acc; epilogue /4096 + bias +
// relu + block-wide row sum-of-squares -> rmsnorm -> coalesced fp32 store.
template <int N>
__global__ __launch_bounds__(512, 2) void k_mfma_rms(
    const float* __restrict__ A, const _Float16* __restrict__ Wt,
    const float* __restrict__ bias, const float* __restrict__ g,
    float* __restrict__ out, int K) {
    constexpr int CT = N / 128;               // col-tiles per wave
    __shared__ __align__(16) _Float16 Bs[2][N * 64];
    __shared__ float ssbuf[64][4];
    const int tid = threadIdx.x;
    const int w = tid >> 6, lane = tid & 63;
    const int wr = w >> 2, wc = w & 3;
    const int g32 = lane >> 5, cl = lane & 31;
    const int row0 = blockIdx.x * 64;
    const int NC = K >> 5;                    // chunks of 32 k (always even)

    const float* ap = A + (size_t)(row0 + wr * 32 + cl) * K + g32 * 8;

    f32x16 acc[CT];
    #pragma unroll
    for (int tt = 0; tt < CT; tt++)
        #pragma unroll
        for (int m = 0; m < 16; m++) acc[tt][m] = 0.f;

    float4 Ar0[4], Ar1[4];

    auto STAGE = [&](int ch, int b) {
        const _Float16* gp = Wt + (size_t)ch * 8 * N * 8;
        #pragma unroll
        for (int p = 0; p < N / 64; p++) {
            int f = tid + 512 * p;
            __builtin_amdgcn_global_load_lds(
                (const __attribute__((address_space(1))) void*)(gp + (size_t)f * 8),
                (__attribute__((address_space(3))) void*)(&Bs[b][(size_t)f * 8]),
                16, 0, 0);
        }
    };
    auto AISSUE = [&](int ch, float4* Ar) {
        const float* bsrc = ap + ch * 32;
        Ar[0] = *(const float4*)(bsrc);
        Ar[1] = *(const float4*)(bsrc + 4);
        Ar[2] = *(const float4*)(bsrc + 16);
        Ar[3] = *(const float4*)(bsrc + 20);
    };
    auto COMPUTE = [&](int b, const float4* Ar) {
        #pragma unroll
        for (int t = 0; t < 2; t++) {
            float vv[8] = {Ar[t * 2].x, Ar[t * 2].y, Ar[t * 2].z, Ar[t * 2].w,
                           Ar[t * 2 + 1].x, Ar[t * 2 + 1].y, Ar[t * 2 + 1].z, Ar[t * 2 + 1].w};
            f16x8 ah, al;
            #pragma unroll
            for (int j = 0; j < 8; j++) {
                float v = vv[j] * 16.f;
                _Float16 h = (_Float16)v;
                ah[j] = h;
                al[j] = (_Float16)(v - (float)h);
            }
            #pragma unroll
            for (int tt = 0; tt < CT; tt++) {
                int c = wc * (N / 4) + tt * 32 + cl;
                f16x8 bh = *(const f16x8*)&Bs[b][((size_t)(t * 2 + g32) * N + c) * 8];
                f16x8 bl = *(const f16x8*)&Bs[b][((size_t)(4 + t * 2 + g32) * N + c) * 8];
                acc[tt] = __builtin_amdgcn_mfma_f32_32x32x16_f16(ah, bh, acc[tt], 0, 0, 0);
                acc[tt] = __builtin_amdgcn_mfma_f32_32x32x16_f16(al, bh, acc[tt], 0, 0, 0);
                acc[tt] = __builtin_amdgcn_mfma_f32_32x32x16_f16(ah, bl, acc[tt], 0, 0, 0);
            }
        }
    };

    AISSUE(0, Ar0);
    STAGE(0, 0);
    for (int ch = 0; ch < NC; ch += 2) {
        __syncthreads();                      // drains stage(ch) + A loads
        STAGE(ch + 1, 1);
        AISSUE(ch + 1, Ar1);
        COMPUTE(0, Ar0);
        __syncthreads();                      // drains stage(ch+1)
        if (ch + 2 < NC) { STAGE(ch + 2, 0); AISSUE(ch + 2, Ar0); }
        COMPUTE(1, Ar1);
    }

    // epilogue: /4096 + bias + relu + rmsnorm
    constexpr float INV = 1.f / 4096.f;
    float bb[CT], gv[CT];
    #pragma unroll
    for (int tt = 0; tt < CT; tt++) {
        int c = wc * (N / 4) + tt * 32 + cl;
        bb[tt] = bias[c];
        gv[tt] = g[c];
    }
    float ssm[16];
    #pragma unroll
    for (int m = 0; m < 16; m++) ssm[m] = 0.f;
    #pragma unroll
    for (int tt = 0; tt < CT; tt++)
        #pragma unroll
        for (int m = 0; m < 16; m++) {
            float v = fmaf(acc[tt][m], INV, bb[tt]);
            v = v > 0.f ? v : 0.f;
            acc[tt][m] = v;
            ssm[m] = fmaf(v, v, ssm[m]);
        }
    #pragma unroll
    for (int mask = 1; mask < 32; mask <<= 1)
        #pragma unroll
        for (int m = 0; m < 16; m++) ssm[m] += __shfl_xor(ssm[m], mask, 64);
    if (cl == 0) {
        #pragma unroll
        for (int m = 0; m < 16; m++) {
            int rl = wr * 32 + (m & 3) + 8 * (m >> 2) + 4 * g32;
            ssbuf[rl][wc] = ssm[m];
        }
    }
    __syncthreads();
    #pragma unroll
    for (int m = 0; m < 16; m++) {
        int rl = wr * 32 + (m & 3) + 8 * (m >> 2) + 4 * g32;
        float s4 = (ssbuf[rl][0] + ssbuf[rl][1]) + (ssbuf[rl][2] + ssbuf[rl][3]);
        float sc = 1.0f / sqrtf(s4 * (1.0f / (float)N) + 1e-6f);
        #pragma unroll
        for (int tt = 0; tt < CT; tt++) {
            int c = wc * (N / 4) + tt * 32 + cl;
            out[(size_t)(row0 + rl) * N + c] = acc[tt][m] * sc * gv[tt];
        }
    }
}

// ---------------- final MFMA Linear (512->768) + recon loss ----------------
// same engine, N-tile 256 over 3 col-blocks; epilogue: bias + loss vs xn + store
__global__ __launch_bounds__(512, 2) void k_mfma_dec2(
    const float* __restrict__ A, const _Float16* __restrict__ Wt,
    const float* __restrict__ bias, float* __restrict__ rec,
    float* __restrict__ loss_acc, int K) {
    constexpr int NT = 256, NF = 768, CT = 2;
    __shared__ __align__(16) _Float16 Bs[2][NT * 64];
    __shared__ float red[8];
    const int tid = threadIdx.x;
    const int w = tid >> 6, lane = tid & 63;
    const int wr = w >> 2, wc = w & 3;
    const int g32 = lane >> 5, cl = lane & 31;
    const int row0 = blockIdx.x * 64;
    const int col0 = blockIdx.y * NT;
    const int NC = K >> 5;

    const float* ap = A + (size_t)(row0 + wr * 32 + cl) * K + g32 * 8;

    f32x16 acc[CT];
    #pragma unroll
    for (int tt = 0; tt < CT; tt++)
        #pragma unroll
        for (int m = 0; m < 16; m++) acc[tt][m] = 0.f;

    float4 Ar0[4], Ar1[4];

    auto STAGE = [&](int ch, int b) {
        #pragma unroll
        for (int p = 0; p < 4; p++) {
            int f = tid + 512 * p;
            int s = f >> 8, cloc = f & 255;
            const _Float16* gp = Wt + ((size_t)(ch * 8 + s) * NF + col0 + cloc) * 8;
            __builtin_amdgcn_global_load_lds(
                (const __attribute__((address_space(1))) void*)gp,
                (__attribute__((address_space(3))) void*)(&Bs[b][(size_t)f * 8]),
                16, 0, 0);
        }
    };
    auto AISSUE = [&](int ch, float4* Ar) {
        const float* bsrc = ap + ch * 32;
        Ar[0] = *(const float4*)(bsrc);
        Ar[1] = *(const float4*)(bsrc + 4);
        Ar[2] = *(const float4*)(bsrc + 16);
        Ar[3] = *(const float4*)(bsrc + 20);
    };
    auto COMPUTE = [&](int b, const float4* Ar) {
        #pragma unroll
        for (int t = 0; t < 2; t++) {
            float vv[8] = {Ar[t * 2].x, Ar[t * 2].y, Ar[t * 2].z, Ar[t * 2].w,
                           Ar[t * 2 + 1].x, Ar[t * 2 + 1].y, Ar[t * 2 + 1].z, Ar[t * 2 + 1].w};
            f16x8 ah, al;
            #pragma unroll
            for (int j = 0; j < 8; j++) {
                float v = vv[j] * 16.f;
                _Float16 h = (_Float16)v;
                ah[j] = h;
                al[j] = (_Float16)(v - (float)h);
            }
            #pragma unroll
            for (int tt = 0; tt < CT; tt++) {
                int c = wc * 64 + tt * 32 + cl;
                f16x8 bh = *(const f16x8*)&Bs[b][((size_t)(t * 2 + g32) * NT + c) * 8];
                f16x8 bl = *(const f16x8*)&Bs[b][((size_t)(4 + t * 2 + g32) * NT + c) * 8];
                acc[tt] = __builtin_amdgcn_mfma_f32_32x32x16_f16(ah, bh, acc[tt], 0, 0, 0);
                acc[tt] = __builtin_amdgcn_mfma_f32_32x32x16_f16(al, bh, acc[tt], 0, 0, 0);
                acc[tt] = __builtin_amdgcn_mfma_f32_32x32x16_f16(ah, bl, acc[tt], 0, 0, 0);
            }
        }
    };

    AISSUE(0, Ar0);
    STAGE(0, 0);
    for (int ch = 0; ch < NC; ch += 2) {
        __syncthreads();
        STAGE(ch + 1, 1);
        AISSUE(ch + 1, Ar1);
        COMPUTE(0, Ar0);
        __syncthreads();
        if (ch + 2 < NC) { STAGE(ch + 2, 0); AISSUE(ch + 2, Ar0); }
        COMPUTE(1, Ar1);
    }

    constexpr float INV = 1.f / 4096.f;
    float lsum = 0.f;
    #pragma unroll
    for (int tt = 0; tt < CT; tt++) {
        int cg = col0 + wc * 64 + tt * 32 + cl;
        float bb = bias[cg];
        #pragma unroll
        for (int m = 0; m < 16; m++) {
            int rl = wr * 32 + (m & 3) + 8 * (m >> 2) + 4 * g32;
            float v = fmaf(acc[tt][m], INV, bb);
            size_t o = (size_t)(row0 + rl) * NF + cg;
            float e = v - rec[o];             // rec holds xn here
            lsum = fmaf(e, e, lsum);
            rec[o] = v;
        }
    }
    #pragma unroll
    for (int mask = 1; mask < 64; mask <<= 1) lsum += __shfl_xor(lsum, mask, 64);
    if (lane == 0) red[w] = lsum;
    __syncthreads();
    if (tid == 0) {
        float t = 0.f;
        #pragma unroll
        for (int i = 0; i < 8; i++) t += red[i];
        atomicAdd(loss_acc, t * (1.0f / ((float)NB * (float)DIN)));
    }
}

// ---------------- VQ: fp16 hi/lo split MFMA scores + partial argmin ----------------
// (unchanged, verified round 1)
__global__ __launch_bounds__(512, 2) void k_vq_argmin_mfma(
    const _Float16* __restrict__ Rsp, const _Float16* __restrict__ Esp,
    const float* __restrict__ cbnS,
    float* __restrict__ pbest, int* __restrict__ pidx) {
    __shared__ __align__(16) _Float16 Es[2][64 * 256];
    const int tid = threadIdx.x;
    const int w = tid >> 6, lane = tid & 63;
    const int wr = w >> 1, wc = w & 1;
    const int g = lane >> 5, cl31 = lane & 31;
    const int row0 = blockIdx.x * 128 + wr * 32;
    const int cbase = blockIdx.y * 4096;

    f16x8 Ah[8], Al[8];
    {
        const _Float16* rp = Rsp + (size_t)(row0 + cl31) * 256 + g * 8;
        #pragma unroll
        for (int kc = 0; kc < 8; kc++) {
            Ah[kc] = *(const f16x8*)(rp + kc * 16);
            Al[kc] = *(const f16x8*)(rp + 128 + kc * 16);
        }
    }

    float best[16];
    int bidx[16];
    #pragma unroll
    for (int m = 0; m < 16; m++) { best[m] = 3.402823466e+38f; bidx[m] = 0; }

    float4 st[4];
    #pragma unroll
    for (int p = 0; p < 4; p++) {
        int f = tid + 512 * p;
        int c = f >> 5, sl = f & 31;
        st[p] = *(const float4*)(Esp + (size_t)(cbase + c) * 256 + sl * 8);
    }
    #pragma unroll
    for (int p = 0; p < 4; p++) {
        int f = tid + 512 * p;
        int c = f >> 5, sl = f & 31;
        *(float4*)&Es[0][c * 256 + ((sl ^ (c & 31)) * 8)] = st[p];
    }
    __syncthreads();

    const int cloc = wc * 32 + cl31;
    const int swz = cloc & 31;

    for (int ch = 0; ch < 64; ch++) {
        const int buf = ch & 1;
        if (ch < 63) {
            #pragma unroll
            for (int p = 0; p < 4; p++) {
                int f = tid + 512 * p;
                int c = f >> 5, sl = f & 31;
                st[p] = *(const float4*)(Esp + (size_t)(cbase + (ch + 1) * 64 + c) * 256 + sl * 8);
            }
        }
        f32x16 a0, a1, a2;
        #pragma unroll
        for (int m = 0; m < 16; m++) { a0[m] = 0.f; a1[m] = 0.f; a2[m] = 0.f; }
        #pragma unroll
        for (int kc = 0; kc < 8; kc++) {
            int sh = kc * 2 + g;
            f16x8 bh = *(const f16x8*)&Es[buf][cloc * 256 + ((sh ^ swz) * 8)];
            f16x8 bl = *(const f16x8*)&Es[buf][cloc * 256 + (((sh + 16) ^ swz) * 8)];
            a0 = __builtin_amdgcn_mfma_f32_32x32x16_f16(Ah[kc], bh, a0, 0, 0, 0);
            a1 = __builtin_amdgcn_mfma_f32_32x32x16_f16(Al[kc], bh, a1, 0, 0, 0);
            a2 = __builtin_amdgcn_mfma_f32_32x32x16_f16(Ah[kc], bl, a2, 0, 0, 0);
        }
        int c = cbase + ch * 64 + cloc;
        float cn = cbnS[c];
        #pragma unroll
        for (int m = 0; m < 16; m++) {
            float s = fmaf(-2.f, a0[m] + a1[m] + a2[m], cn);
            if (s < best[m]) { best[m] = s; bidx[m] = c; }
        }
        if (ch < 63) {
            __syncthreads();
            #pragma unroll
            for (int p = 0; p < 4; p++) {
                int f = tid + 512 * p;
                int cc = f >> 5, sl = f & 31;
                *(float4*)&Es[buf ^ 1][cc * 256 + ((sl ^ (cc & 31)) * 8)] = st[p];
            }
            __syncthreads();
        }
    }

    #pragma unroll
    for (int mask = 1; mask < 32; mask <<= 1) {
        #pragma unroll
        for (int m = 0; m < 16; m++) {
            float ob = __shfl_xor(best[m], mask, 64);
            int oi = __shfl_xor(bidx[m], mask, 64);
            if (ob < best[m] || (ob == best[m] && oi < bidx[m])) { best[m] = ob; bidx[m] = oi; }
        }
    }
    if (cl31 == 0) {
        int part = blockIdx.y * 2 + wc;
        #pragma unroll
        for (int m = 0; m < 16; m++) {
            int row = row0 + (m & 3) + 8 * (m >> 2) + 4 * g;
            pbest[(size_t)part * NB + row] = best[m];
            pidx[(size_t)part * NB + row] = bidx[m];
        }
    }
}

// merge the 4 partials; tie -> smaller index
__global__ void k_vq_reduce(const float* __restrict__ pbest, const int* __restrict__ pidx,
                            int* __restrict__ idx_out, float* __restrict__ ids_f) {
    int row = blockIdx.x * 256 + threadIdx.x;
    float b = pbest[row];
    int bi = pidx[row];
    #pragma unroll
    for (int s = 1; s < 4; s++) {
        float ob = pbest[(size_t)s * NB + row];
        int oi = pidx[(size_t)s * NB + row];
        if (ob < b || (ob == b && oi < bi)) { b = ob; bi = oi; }
    }
    idx_out[row] = bi;
    ids_f[(size_t)row * 4] = (float)bi;
}

// gather + residual update + qsum + vq_loss partial; writes fp16 split (x16)
__global__ void k_vq_update(const float* __restrict__ Rin, const int* __restrict__ idx,
                            const float* __restrict__ E, float* __restrict__ Rout,
                            float* __restrict__ qsum, float* __restrict__ vq_acc,
                            int firstq, _Float16* __restrict__ Rsp) {
    __shared__ float ps[4];
    int i = blockIdx.x * 256 + threadIdx.x;   // NB*128 total
    int row = i >> 7, d = i & 127;
    float e = E[(size_t)idx[row] * 128 + d];
    float rv = Rin[i] - e;
    Rout[i] = rv;
    qsum[i] = firstq ? e : (qsum[i] + e);
    float rs = rv * 16.f;
    _Float16 hi = (_Float16)rs;
    Rsp[(size_t)row * 256 + d] = hi;
    Rsp[(size_t)row * 256 + 128 + d] = (_Float16)(rs - (float)hi);
    float p = rv * rv;
    #pragma unroll
    for (int m = 1; m < 64; m <<= 1) p += __shfl_xor(p, m, 64);
    int lane = threadIdx.x & 63, wv = threadIdx.x >> 6;
    if (lane == 0) ps[wv] = p;
    __syncthreads();
    if (threadIdx.x == 0)
        atomicAdd(vq_acc, (ps[0] + ps[1] + ps[2] + ps[3]) * (1.25f / ((float)NB * 128.f)));
}

// ---------------- launch ----------------

extern "C" void kernel_launch(void* const* d_in, const int* in_sizes, int n_in,
                              void* d_out, int out_size, void* d_ws, size_t ws_size,
                              hipStream_t stream) {
    (void)in_sizes; (void)n_in; (void)out_size; (void)ws_size;
    const float* x        = (const float*)d_in[0];
    const float* emb_mean = (const float*)d_in[1];
    const float* emb_std  = (const float*)d_in[2];
    const float* enc_w0 = (const float*)d_in[3];
    const float* enc_b0 = (const float*)d_in[4];
    const float* enc_g0 = (const float*)d_in[5];
    const float* enc_w1 = (const float*)d_in[6];
    const float* enc_b1 = (const float*)d_in[7];
    const float* enc_g1 = (const float*)d_in[8];
    const float* enc_w2 = (const float*)d_in[9];
    const float* enc_b2 = (const float*)d_in[10];
    const float* enc_g2 = (const float*)d_in[11];
    const float* cb     = (const float*)d_in[12];
    const float* dec_w0 = (const float*)d_in[13];
    const float* dec_b0 = (const float*)d_in[14];
    const float* dec_g0 = (const float*)d_in[15];
    const float* dec_w1 = (const float*)d_in[16];
    const float* dec_b1 = (const float*)d_in[17];
    const float* dec_g1 = (const float*)d_in[18];
    const float* dec_w2 = (const float*)d_in[19];
    const float* dec_b2 = (const float*)d_in[20];

    float* out   = (float*)d_out;
    float* xn    = out;                        // recon region doubles as xn scratch
    float* ids_f = out + (size_t)NB * DIN;
    float* rl    = out + (size_t)NB * DIN + (size_t)NB * 4;
    float* vl    = rl + 1;

    float* ws   = (float*)d_ws;
    float* h0   = ws;                           // 16384*512
    float* h1   = h0 + (size_t)NB * 512;        // 16384*256
    float* h2   = h1 + (size_t)NB * 256;        // 16384*128
    float* rbuf = h2 + (size_t)NB * 128;        // 16384*128
    float* qsum = rbuf + (size_t)NB * 128;      // 16384*128
    float* cbn  = qsum + (size_t)NB * 128;      // 4*8192
    int*   idxb = (int*)(cbn + 4 * 8192);       // 16384

    // VQ scratch in h0 (free between enc1-read and dec1-write)
    float*    pbest = h0;                                   // 4*16384
    int*      pidx  = (int*)(h0 + 4 * (size_t)NB);          // 4*16384
    _Float16* Rsp   = (_Float16*)(h0 + 8 * (size_t)NB);     // NB*256 halfs
    _Float16* Esp   = (_Float16*)(h0 + 8 * (size_t)NB + (size_t)NB * 128);

    // weight splits live in rbuf: enc set dead before VQ writes rbuf (q=0
    // update); dec set written after the last vq_update reads rbuf.
    _Float16* WtE0 = (_Float16*)rbuf;           // 768*512*2 = 786432 halfs
    _Float16* WtE1 = WtE0 + 786432;             // 512*256*2 = 262144
    _Float16* WtE2 = WtE0 + 1048576;            // 256*128*2 =  65536
    _Float16* WtD0 = (_Float16*)rbuf;           // 128*256*2 =  65536
    _Float16* WtD1 = WtD0 + 65536;              // 256*512*2 = 262144
    _Float16* WtD2 = WtD0 + 327680;             // 512*768*2 = 786432

    k_zero2<<<1, 64, 0, stream>>>(rl, vl);
    k_norm<<<(NB * DIN) / 256, 256, 0, stream>>>(x, emb_mean, emb_std, xn);
    k_cbnorm<<<(4 * 8192) / 4, 256, 0, stream>>>(cb, cbn);

    k_wsplit<<<(768 * 512) / 256, 256, 0, stream>>>(enc_w0, WtE0, 768, 512);
    k_wsplit<<<(512 * 256) / 256, 256, 0, stream>>>(enc_w1, WtE1, 512, 256);
    k_wsplit<<<(256 * 128) / 256, 256, 0, stream>>>(enc_w2, WtE2, 256, 128);

    k_mfma_rms<512><<<NB / 64, 512, 0, stream>>>(xn, WtE0, enc_b0, enc_g0, h0, 768);
    k_mfma_rms<256><<<NB / 64, 512, 0, stream>>>(h0, WtE1, enc_b1, enc_g1, h1, 512);
    k_mfma_rms<128><<<NB / 64, 512, 0, stream>>>(h1, WtE2, enc_b2, enc_g2, h2, 256);

    // fp16 splits for VQ (into h0 region, after enc1 consumed h0)
    k_split<<<(4 * 8192 * 128) / 256, 256, 0, stream>>>(cb, Esp, 256.f);
    k_split<<<(NB * 128) / 256, 256, 0, stream>>>(h2, Rsp, 16.f);

    for (int q = 0; q < 4; q++) {
        const float* R = (q == 0) ? h2 : rbuf;
        const float* Eq = cb + (size_t)q * 8192 * 128;
        const _Float16* EspQ = Esp + (size_t)q * 8192 * 256;
        dim3 gq(NB / 128, 2);
        k_vq_argmin_mfma<<<gq, 512, 0, stream>>>(Rsp, EspQ, cbn + q * 8192, pbest, pidx);
        k_vq_reduce<<<NB / 256, 256, 0, stream>>>(pbest, pidx, idxb, ids_f + q);
        k_vq_update<<<(NB * 128) / 256, 256, 0, stream>>>(R, idxb, Eq, rbuf, qsum, vl,
                                                          q == 0 ? 1 : 0, Rsp);
    }

    // dec weight splits (rbuf dead after last vq_update)
    k_wsplit<<<(128 * 256) / 256, 256, 0, stream>>>(dec_w0, WtD0, 128, 256);
    k_wsplit<<<(256 * 512) / 256, 256, 0, stream>>>(dec_w1, WtD1, 256, 512);
    k_wsplit<<<(512 * 768) / 256, 256, 0, stream>>>(dec_w2, WtD2, 512, 768);

    k_mfma_rms<256><<<NB / 64, 512, 0, stream>>>(qsum, WtD0, dec_b0, dec_g0, h1, 128);
    k_mfma_rms<512><<<NB / 64, 512, 0, stream>>>(h1, WtD1, dec_b1, dec_g1, h0, 256);

    dim3 g2(NB / 64, 3);
    k_mfma_dec2<<<g2, 512, 0, stream>>>(h0, WtD2, dec_b2, xn, rl, 512);
}

// Round 3
// 1393.712 us; speedup vs baseline: 2.3360x; 1.1585x over previous
//
#include <hip/hip_runtime.h>
#include <math.h>

#define NB 16384
#define DIN 768

typedef _Float16 f16x8 __attribute__((ext_vector_type(8)));
typedef float f32x16 __attribute__((ext_vector_type(16)));

// ---------------- small kernels ----------------

__global__ void k_zero2(float* a, float* b) {
    if (threadIdx.x == 0) { *a = 0.f; *b = 0.f; }
}

__global__ void k_norm(const float* __restrict__ x, const float* __restrict__ m,
                       const float* __restrict__ s, float* __restrict__ xn) {
    int i = blockIdx.x * 256 + threadIdx.x;          // 16384*768 total
    int j = i % DIN;
    xn[i] = (x[i] - m[j]) / s[j];
}

// one 64-lane wave per codebook row; writes ||E||^2 * 4096 (r*-32, E*256 scaling)
__global__ void k_cbnorm(const float* __restrict__ cb, float* __restrict__ cbn) {
    int row = blockIdx.x * 4 + (threadIdx.x >> 6);
    int lane = threadIdx.x & 63;
    const float* p = cb + (size_t)row * 128;
    float v0 = p[lane], v1 = p[lane + 64];
    float s = v0 * v0 + v1 * v1;
    #pragma unroll
    for (int m = 32; m >= 1; m >>= 1) s += __shfl_xor(s, m, 64);
    if (lane == 0) cbn[row] = s * 4096.f;
}

// split fp32 rows (n x 128) into fp16 hi|lo layout (n x 256): [hi(128) | lo(128)]
__global__ void k_split(const float* __restrict__ src, _Float16* __restrict__ dst,
                        float scale) {
    int i = blockIdx.x * 256 + threadIdx.x;   // n*128 elements
    int row = i >> 7, d = i & 127;
    float v = src[i] * scale;
    _Float16 hi = (_Float16)v;
    dst[(size_t)row * 256 + d] = hi;
    dst[(size_t)row * 256 + 128 + d] = (_Float16)(v - (float)hi);
}

// E split into per-chunk granule layout consumed linearly by global_load_lds:
// per quantizer, chunk ch (64 codes): halfs offset = ch*16384 + sh*512 + cloc*8 + j
// where sh = k>>3 (hi) / 16+(k>>3) (lo), cloc = c&63, j = k&7. Scale 256.
__global__ void k_esplit(const float* __restrict__ cb, _Float16* __restrict__ Esp) {
    int i = blockIdx.x * 256 + threadIdx.x;   // 4*8192*128 total
    int q = i >> 20;
    int rem = i & 1048575;
    int c = rem >> 7, k = rem & 127;
    float v = cb[i] * 256.f;
    _Float16 hi = (_Float16)v;
    _Float16 lo = (_Float16)(v - (float)hi);
    int ch = c >> 6, cloc = c & 63;
    int sh = k >> 3, j = k & 7;
    size_t base = (size_t)q * 2097152 + (size_t)ch * 16384 + (size_t)cloc * 8 + j;
    Esp[base + (size_t)sh * 512] = hi;
    Esp[base + (size_t)(16 + sh) * 512] = lo;
}

// ---------------- weight transpose-split into chunked granule layout ----------
// W (K x N fp32) -> Wt halfs, granule (kc, s, c): ((kc*8+s)*N + c)*8 + j
// k = kc*32 + t*16 + g*8 + j ; s = t*2+g (hi), 4+t*2+g (lo). Scale 256.
__global__ void k_wsplit(const float* __restrict__ W, _Float16* __restrict__ Wt,
                         int K, int N) {
    int i = blockIdx.x * 256 + threadIdx.x;   // K*N total
    int k = i / N, c = i - k * N;
    float v = W[i] * 256.f;
    _Float16 hi = (_Float16)v;
    _Float16 lo = (_Float16)(v - (float)hi);
    int kc = k >> 5, kin = k & 31;
    int t = kin >> 4, gg = (kin >> 3) & 1, j = kin & 7;
    size_t base = ((size_t)(kc * 8) * N + c) * 8 + j;
    Wt[base + (size_t)(t * 2 + gg) * N * 8] = hi;
    Wt[base + (size_t)(4 + t * 2 + gg) * N * 8] = lo;
}

// ---------------- fused MFMA Linear + ReLU + RMSNorm ----------------
// (unchanged, verified round 2)
template <int N>
__global__ __launch_bounds__(512, 2) void k_mfma_rms(
    const float* __restrict__ A, const _Float16* __restrict__ Wt,
    const float* __restrict__ bias, const float* __restrict__ g,
    float* __restrict__ out, int K) {
    constexpr int CT = N / 128;               // col-tiles per wave
    __shared__ __align__(16) _Float16 Bs[2][N * 64];
    __shared__ float ssbuf[64][4];
    const int tid = threadIdx.x;
    const int w = tid >> 6, lane = tid & 63;
    const int wr = w >> 2, wc = w & 3;
    const int g32 = lane >> 5, cl = lane & 31;
    const int row0 = blockIdx.x * 64;
    const int NC = K >> 5;                    // chunks of 32 k (always even)

    const float* ap = A + (size_t)(row0 + wr * 32 + cl) * K + g32 * 8;

    f32x16 acc[CT];
    #pragma unroll
    for (int tt = 0; tt < CT; tt++)
        #pragma unroll
        for (int m = 0; m < 16; m++) acc[tt][m] = 0.f;

    float4 Ar0[4], Ar1[4];

    auto STAGE = [&](int ch, int b) {
        const _Float16* gp = Wt + (size_t)ch * 8 * N * 8;
        #pragma unroll
        for (int p = 0; p < N / 64; p++) {
            int f = tid + 512 * p;
            __builtin_amdgcn_global_load_lds(
                (const __attribute__((address_space(1))) void*)(gp + (size_t)f * 8),
                (__attribute__((address_space(3))) void*)(&Bs[b][(size_t)f * 8]),
                16, 0, 0);
        }
    };
    auto AISSUE = [&](int ch, float4* Ar) {
        const float* bsrc = ap + ch * 32;
        Ar[0] = *(const float4*)(bsrc);
        Ar[1] = *(const float4*)(bsrc + 4);
        Ar[2] = *(const float4*)(bsrc + 16);
        Ar[3] = *(const float4*)(bsrc + 20);
    };
    auto COMPUTE = [&](int b, const float4* Ar) {
        #pragma unroll
        for (int t = 0; t < 2; t++) {
            float vv[8] = {Ar[t * 2].x, Ar[t * 2].y, Ar[t * 2].z, Ar[t * 2].w,
                           Ar[t * 2 + 1].x, Ar[t * 2 + 1].y, Ar[t * 2 + 1].z, Ar[t * 2 + 1].w};
            f16x8 ah, al;
            #pragma unroll
            for (int j = 0; j < 8; j++) {
                float v = vv[j] * 16.f;
                _Float16 h = (_Float16)v;
                ah[j] = h;
                al[j] = (_Float16)(v - (float)h);
            }
            #pragma unroll
            for (int tt = 0; tt < CT; tt++) {
                int c = wc * (N / 4) + tt * 32 + cl;
                f16x8 bh = *(const f16x8*)&Bs[b][((size_t)(t * 2 + g32) * N + c) * 8];
                f16x8 bl = *(const f16x8*)&Bs[b][((size_t)(4 + t * 2 + g32) * N + c) * 8];
                acc[tt] = __builtin_amdgcn_mfma_f32_32x32x16_f16(ah, bh, acc[tt], 0, 0, 0);
                acc[tt] = __builtin_amdgcn_mfma_f32_32x32x16_f16(al, bh, acc[tt], 0, 0, 0);
                acc[tt] = __builtin_amdgcn_mfma_f32_32x32x16_f16(ah, bl, acc[tt], 0, 0, 0);
            }
        }
    };

    AISSUE(0, Ar0);
    STAGE(0, 0);
    for (int ch = 0; ch < NC; ch += 2) {
        __syncthreads();                      // drains stage(ch) + A loads
        STAGE(ch + 1, 1);
        AISSUE(ch + 1, Ar1);
        COMPUTE(0, Ar0);
        __syncthreads();                      // drains stage(ch+1)
        if (ch + 2 < NC) { STAGE(ch + 2, 0); AISSUE(ch + 2, Ar0); }
        COMPUTE(1, Ar1);
    }

    // epilogue: /4096 + bias + relu + rmsnorm
    constexpr float INV = 1.f / 4096.f;
    float bb[CT], gv[CT];
    #pragma unroll
    for (int tt = 0; tt < CT; tt++) {
        int c = wc * (N / 4) + tt * 32 + cl;
        bb[tt] = bias[c];
        gv[tt] = g[c];
    }
    float ssm[16];
    #pragma unroll
    for (int m = 0; m < 16; m++) ssm[m] = 0.f;
    #pragma unroll
    for (int tt = 0; tt < CT; tt++)
        #pragma unroll
        for (int m = 0; m < 16; m++) {
            float v = fmaf(acc[tt][m], INV, bb[tt]);
            v = v > 0.f ? v : 0.f;
            acc[tt][m] = v;
            ssm[m] = fmaf(v, v, ssm[m]);
        }
    #pragma unroll
    for (int mask = 1; mask < 32; mask <<= 1)
        #pragma unroll
        for (int m = 0; m < 16; m++) ssm[m] += __shfl_xor(ssm[m], mask, 64);
    if (cl == 0) {
        #pragma unroll
        for (int m = 0; m < 16; m++) {
            int rl = wr * 32 + (m & 3) + 8 * (m >> 2) + 4 * g32;
            ssbuf[rl][wc] = ssm[m];
        }
    }
    __syncthreads();
    #pragma unroll
    for (int m = 0; m < 16; m++) {
        int rl = wr * 32 + (m & 3) + 8 * (m >> 2) + 4 * g32;
        float s4 = (ssbuf[rl][0] + ssbuf[rl][1]) + (ssbuf[rl][2] + ssbuf[rl][3]);
        float sc = 1.0f / sqrtf(s4 * (1.0f / (float)N) + 1e-6f);
        #pragma unroll
        for (int tt = 0; tt < CT; tt++) {
            int c = wc * (N / 4) + tt * 32 + cl;
            out[(size_t)(row0 + rl) * N + c] = acc[tt][m] * sc * gv[tt];
        }
    }
}

// ---------------- final MFMA Linear (512->768) + recon loss ----------------
// (unchanged, verified round 2)
__global__ __launch_bounds__(512, 2) void k_mfma_dec2(
    const float* __restrict__ A, const _Float16* __restrict__ Wt,
    const float* __restrict__ bias, float* __restrict__ rec,
    float* __restrict__ loss_acc, int K) {
    constexpr int NT = 256, NF = 768, CT = 2;
    __shared__ __align__(16) _Float16 Bs[2][NT * 64];
    __shared__ float red[8];
    const int tid = threadIdx.x;
    const int w = tid >> 6, lane = tid & 63;
    const int wr = w >> 2, wc = w & 3;
    const int g32 = lane >> 5, cl = lane & 31;
    const int row0 = blockIdx.x * 64;
    const int col0 = blockIdx.y * NT;
    const int NC = K >> 5;

    const float* ap = A + (size_t)(row0 + wr * 32 + cl) * K + g32 * 8;

    f32x16 acc[CT];
    #pragma unroll
    for (int tt = 0; tt < CT; tt++)
        #pragma unroll
        for (int m = 0; m < 16; m++) acc[tt][m] = 0.f;

    float4 Ar0[4], Ar1[4];

    auto STAGE = [&](int ch, int b) {
        #pragma unroll
        for (int p = 0; p < 4; p++) {
            int f = tid + 512 * p;
            int s = f >> 8, cloc = f & 255;
            const _Float16* gp = Wt + ((size_t)(ch * 8 + s) * NF + col0 + cloc) * 8;
            __builtin_amdgcn_global_load_lds(
                (const __attribute__((address_space(1))) void*)gp,
                (__attribute__((address_space(3))) void*)(&Bs[b][(size_t)f * 8]),
                16, 0, 0);
        }
    };
    auto AISSUE = [&](int ch, float4* Ar) {
        const float* bsrc = ap + ch * 32;
        Ar[0] = *(const float4*)(bsrc);
        Ar[1] = *(const float4*)(bsrc + 4);
        Ar[2] = *(const float4*)(bsrc + 16);
        Ar[3] = *(const float4*)(bsrc + 20);
    };
    auto COMPUTE = [&](int b, const float4* Ar) {
        #pragma unroll
        for (int t = 0; t < 2; t++) {
            float vv[8] = {Ar[t * 2].x, Ar[t * 2].y, Ar[t * 2].z, Ar[t * 2].w,
                           Ar[t * 2 + 1].x, Ar[t * 2 + 1].y, Ar[t * 2 + 1].z, Ar[t * 2 + 1].w};
            f16x8 ah, al;
            #pragma unroll
            for (int j = 0; j < 8; j++) {
                float v = vv[j] * 16.f;
                _Float16 h = (_Float16)v;
                ah[j] = h;
                al[j] = (_Float16)(v - (float)h);
            }
            #pragma unroll
            for (int tt = 0; tt < CT; tt++) {
                int c = wc * 64 + tt * 32 + cl;
                f16x8 bh = *(const f16x8*)&Bs[b][((size_t)(t * 2 + g32) * NT + c) * 8];
                f16x8 bl = *(const f16x8*)&Bs[b][((size_t)(4 + t * 2 + g32) * NT + c) * 8];
                acc[tt] = __builtin_amdgcn_mfma_f32_32x32x16_f16(ah, bh, acc[tt], 0, 0, 0);
                acc[tt] = __builtin_amdgcn_mfma_f32_32x32x16_f16(al, bh, acc[tt], 0, 0, 0);
                acc[tt] = __builtin_amdgcn_mfma_f32_32x32x16_f16(ah, bl, acc[tt], 0, 0, 0);
            }
        }
    };

    AISSUE(0, Ar0);
    STAGE(0, 0);
    for (int ch = 0; ch < NC; ch += 2) {
        __syncthreads();
        STAGE(ch + 1, 1);
        AISSUE(ch + 1, Ar1);
        COMPUTE(0, Ar0);
        __syncthreads();
        if (ch + 2 < NC) { STAGE(ch + 2, 0); AISSUE(ch + 2, Ar0); }
        COMPUTE(1, Ar1);
    }

    constexpr float INV = 1.f / 4096.f;
    float lsum = 0.f;
    #pragma unroll
    for (int tt = 0; tt < CT; tt++) {
        int cg = col0 + wc * 64 + tt * 32 + cl;
        float bb = bias[cg];
        #pragma unroll
        for (int m = 0; m < 16; m++) {
            int rl = wr * 32 + (m & 3) + 8 * (m >> 2) + 4 * g32;
            float v = fmaf(acc[tt][m], INV, bb);
            size_t o = (size_t)(row0 + rl) * NF + cg;
            float e = v - rec[o];             // rec holds xn here
            lsum = fmaf(e, e, lsum);
            rec[o] = v;
        }
    }
    #pragma unroll
    for (int mask = 1; mask < 64; mask <<= 1) lsum += __shfl_xor(lsum, mask, 64);
    if (lane == 0) red[w] = lsum;
    __syncthreads();
    if (tid == 0) {
        float t = 0.f;
        #pragma unroll
        for (int i = 0; i < 8; i++) t += red[i];
        atomicAdd(loss_acc, t * (1.0f / ((float)NB * (float)DIN)));
    }
}

// ---------------- VQ: fp16 hi/lo split MFMA scores + partial argmin (v2) -----
// score = 4096||E||^2 + (-32 r)·(256 E) = cbn - 2*4096 r·E  (-2 folded into R scale)
// grid (NB/128, 8 strips of 1024 codes) = 1024 blocks; block 512 = 8 waves.
// wr = w>>1 (4 row-groups of 32), wc = w&1 (code half of 64-chunk).
// Esp pre-arranged per-chunk granule order -> staging is a LINEAR
// global_load_lds copy (no regs, no ds_write), ONE barrier per chunk.
// Frag reads: 32 lanes read contiguous 512B -> conflict-free.
// 2 accumulator chains (ah*[bh], al*[bh] share a0; ah*bl in a1).
__global__ __launch_bounds__(512, 2) void k_vq_argmin_mfma(
    const _Float16* __restrict__ Rsp, const _Float16* __restrict__ Esp,
    const float* __restrict__ cbnS,
    float* __restrict__ pbest, int* __restrict__ pidx) {
    __shared__ __align__(16) _Float16 Es[2][16384];   // 2 x 32KB
    const int tid = threadIdx.x;
    const int w = tid >> 6, lane = tid & 63;
    const int wr = w >> 1, wc = w & 1;
    const int g = lane >> 5, cl31 = lane & 31;
    const int row0 = blockIdx.x * 128 + wr * 32;
    const int cbase = blockIdx.y * 1024;
    const int ch0 = blockIdx.y * 16;

    // A fragments: row = row0 + (lane&31), k-group g (8 halfs per kc)
    f16x8 Ah[8], Al[8];
    {
        const _Float16* rp = Rsp + (size_t)(row0 + cl31) * 256 + g * 8;
        #pragma unroll
        for (int kc = 0; kc < 8; kc++) {
            Ah[kc] = *(const f16x8*)(rp + kc * 16);
            Al[kc] = *(const f16x8*)(rp + 128 + kc * 16);
        }
    }

    float best[16];
    int bidx[16];
    #pragma unroll
    for (int m = 0; m < 16; m++) { best[m] = 3.402823466e+38f; bidx[m] = 0; }

    auto STAGE = [&](int gch, int b) {
        const _Float16* gp = Esp + (size_t)gch * 16384;
        #pragma unroll
        for (int p = 0; p < 4; p++) {
            int f = tid + 512 * p;
            __builtin_amdgcn_global_load_lds(
                (const __attribute__((address_space(1))) void*)(gp + (size_t)f * 8),
                (__attribute__((address_space(3))) void*)(&Es[b][(size_t)f * 8]),
                16, 0, 0);
        }
    };

    const int cloc = wc * 32 + cl31;          // code within the 64-chunk

    STAGE(ch0, 0);
    for (int ch = 0; ch < 16; ch++) {
        const int buf = ch & 1;
        __syncthreads();                      // stage(ch) landed; buf free to read
        if (ch < 15) STAGE(ch0 + ch + 1, buf ^ 1);
        int c = cbase + ch * 64 + cloc;
        float cn = cbnS[c];
        f32x16 a0, a1;
        #pragma unroll
        for (int m = 0; m < 16; m++) { a0[m] = 0.f; a1[m] = 0.f; }
        #pragma unroll
        for (int kc = 0; kc < 8; kc++) {
            int sh = kc * 2 + g;
            f16x8 bh = *(const f16x8*)&Es[buf][(size_t)sh * 512 + cloc * 8];
            f16x8 bl = *(const f16x8*)&Es[buf][(size_t)(16 + sh) * 512 + cloc * 8];
            a0 = __builtin_amdgcn_mfma_f32_32x32x16_f16(Ah[kc], bh, a0, 0, 0, 0);
            a0 = __builtin_amdgcn_mfma_f32_32x32x16_f16(Al[kc], bh, a0, 0, 0, 0);
            a1 = __builtin_amdgcn_mfma_f32_32x32x16_f16(Ah[kc], bl, a1, 0, 0, 0);
        }
        // running argmin; codes ascending per thread -> strict < keeps first
        #pragma unroll
        for (int m = 0; m < 16; m++) {
            float s = (a0[m] + a1[m]) + cn;
            if (s < best[m]) { best[m] = s; bidx[m] = c; }
        }
    }

    // reduce across 32 code-lanes (xor masks < 32 stay within lane-half);
    // tie -> smaller index (numpy first-occurrence)
    #pragma unroll
    for (int mask = 1; mask < 32; mask <<= 1) {
        #pragma unroll
        for (int m = 0; m < 16; m++) {
            float ob = __shfl_xor(best[m], mask, 64);
            int oi = __shfl_xor(bidx[m], mask, 64);
            if (ob < best[m] || (ob == best[m] && oi < bidx[m])) { best[m] = ob; bidx[m] = oi; }
        }
    }
    if (cl31 == 0) {
        int part = blockIdx.y * 2 + wc;
        // C/D layout (m74): row = (reg&3) + 8*(reg>>2) + 4*(lane>>5)
        #pragma unroll
        for (int m = 0; m < 16; m++) {
            int row = row0 + (m & 3) + 8 * (m >> 2) + 4 * g;
            pbest[(size_t)part * NB + row] = best[m];
            pidx[(size_t)part * NB + row] = bidx[m];
        }
    }
}

// merge the 16 partials (8 strips x 2 wave-halves); tie -> smaller index
__global__ void k_vq_reduce(const float* __restrict__ pbest, const int* __restrict__ pidx,
                            int* __restrict__ idx_out, float* __restrict__ ids_f) {
    int row = blockIdx.x * 256 + threadIdx.x;
    float b = pbest[row];
    int bi = pidx[row];
    #pragma unroll
    for (int s = 1; s < 16; s++) {
        float ob = pbest[(size_t)s * NB + row];
        int oi = pidx[(size_t)s * NB + row];
        if (ob < b || (ob == b && oi < bi)) { b = ob; bi = oi; }
    }
    idx_out[row] = bi;
    ids_f[(size_t)row * 4] = (float)bi;
}

// gather + residual update + qsum + vq_loss partial; writes fp16 split (x -32)
__global__ void k_vq_update(const float* __restrict__ Rin, const int* __restrict__ idx,
                            const float* __restrict__ E, float* __restrict__ Rout,
                            float* __restrict__ qsum, float* __restrict__ vq_acc,
                            int firstq, _Float16* __restrict__ Rsp) {
    __shared__ float ps[4];
    int i = blockIdx.x * 256 + threadIdx.x;   // NB*128 total
    int row = i >> 7, d = i & 127;
    float e = E[(size_t)idx[row] * 128 + d];
    float rv = Rin[i] - e;
    Rout[i] = rv;
    qsum[i] = firstq ? e : (qsum[i] + e);
    float rs = rv * -32.f;
    _Float16 hi = (_Float16)rs;
    Rsp[(size_t)row * 256 + d] = hi;
    Rsp[(size_t)row * 256 + 128 + d] = (_Float16)(rs - (float)hi);
    float p = rv * rv;
    #pragma unroll
    for (int m = 1; m < 64; m <<= 1) p += __shfl_xor(p, m, 64);
    int lane = threadIdx.x & 63, wv = threadIdx.x >> 6;
    if (lane == 0) ps[wv] = p;
    __syncthreads();
    if (threadIdx.x == 0)
        atomicAdd(vq_acc, (ps[0] + ps[1] + ps[2] + ps[3]) * (1.25f / ((float)NB * 128.f)));
}

// ---------------- launch ----------------

extern "C" void kernel_launch(void* const* d_in, const int* in_sizes, int n_in,
                              void* d_out, int out_size, void* d_ws, size_t ws_size,
                              hipStream_t stream) {
    (void)in_sizes; (void)n_in; (void)out_size; (void)ws_size;
    const float* x        = (const float*)d_in[0];
    const float* emb_mean = (const float*)d_in[1];
    const float* emb_std  = (const float*)d_in[2];
    const float* enc_w0 = (const float*)d_in[3];
    const float* enc_b0 = (const float*)d_in[4];
    const float* enc_g0 = (const float*)d_in[5];
    const float* enc_w1 = (const float*)d_in[6];
    const float* enc_b1 = (const float*)d_in[7];
    const float* enc_g1 = (const float*)d_in[8];
    const float* enc_w2 = (const float*)d_in[9];
    const float* enc_b2 = (const float*)d_in[10];
    const float* enc_g2 = (const float*)d_in[11];
    const float* cb     = (const float*)d_in[12];
    const float* dec_w0 = (const float*)d_in[13];
    const float* dec_b0 = (const float*)d_in[14];
    const float* dec_g0 = (const float*)d_in[15];
    const float* dec_w1 = (const float*)d_in[16];
    const float* dec_b1 = (const float*)d_in[17];
    const float* dec_g1 = (const float*)d_in[18];
    const float* dec_w2 = (const float*)d_in[19];
    const float* dec_b2 = (const float*)d_in[20];

    float* out   = (float*)d_out;
    float* xn    = out;                        // recon region doubles as xn scratch
    float* ids_f = out + (size_t)NB * DIN;
    float* rl    = out + (size_t)NB * DIN + (size_t)NB * 4;
    float* vl    = rl + 1;

    float* ws   = (float*)d_ws;
    float* h0   = ws;                           // 16384*512
    float* h1   = h0 + (size_t)NB * 512;        // 16384*256
    float* h2   = h1 + (size_t)NB * 256;        // 16384*128
    float* rbuf = h2 + (size_t)NB * 128;        // 16384*128
    float* qsum = rbuf + (size_t)NB * 128;      // 16384*128
    float* cbn  = qsum + (size_t)NB * 128;      // 4*8192
    int*   idxb = (int*)(cbn + 4 * 8192);       // 16384

    // VQ scratch in h0 (free between enc1-read and dec1-write):
    //   pbest 16*NB f, pidx 16*NB i, Rsp NB*256 halfs, Esp 4*8192*256 halfs
    //   = 0.52M + 2.10M + 4.19M float-equiv = 6.82M < 8.39M.
    float*    pbest = h0;                                   // 16*16384
    int*      pidx  = (int*)(h0 + 16 * (size_t)NB);         // 16*16384
    _Float16* Rsp   = (_Float16*)(h0 + 32 * (size_t)NB);
    _Float16* Esp   = (_Float16*)(h0 + 32 * (size_t)NB + (size_t)NB * 128);

    // weight splits live in rbuf: enc set dead before VQ writes rbuf (q=0
    // update); dec set written after the last vq_update reads rbuf.
    _Float16* WtE0 = (_Float16*)rbuf;           // 768*512*2 = 786432 halfs
    _Float16* WtE1 = WtE0 + 786432;             // 512*256*2 = 262144
    _Float16* WtE2 = WtE0 + 1048576;            // 256*128*2 =  65536
    _Float16* WtD0 = (_Float16*)rbuf;           // 128*256*2 =  65536
    _Float16* WtD1 = WtD0 + 65536;              // 256*512*2 = 262144
    _Float16* WtD2 = WtD0 + 327680;             // 512*768*2 = 786432

    k_zero2<<<1, 64, 0, stream>>>(rl, vl);
    k_norm<<<(NB * DIN) / 256, 256, 0, stream>>>(x, emb_mean, emb_std, xn);
    k_cbnorm<<<(4 * 8192) / 4, 256, 0, stream>>>(cb, cbn);

    k_wsplit<<<(768 * 512) / 256, 256, 0, stream>>>(enc_w0, WtE0, 768, 512);
    k_wsplit<<<(512 * 256) / 256, 256, 0, stream>>>(enc_w1, WtE1, 512, 256);
    k_wsplit<<<(256 * 128) / 256, 256, 0, stream>>>(enc_w2, WtE2, 256, 128);

    k_mfma_rms<512><<<NB / 64, 512, 0, stream>>>(xn, WtE0, enc_b0, enc_g0, h0, 768);
    k_mfma_rms<256><<<NB / 64, 512, 0, stream>>>(h0, WtE1, enc_b1, enc_g1, h1, 512);
    k_mfma_rms<128><<<NB / 64, 512, 0, stream>>>(h1, WtE2, enc_b2, enc_g2, h2, 256);

    // fp16 splits for VQ (into h0 region, after enc1 consumed h0)
    k_esplit<<<(4 * 8192 * 128) / 256, 256, 0, stream>>>(cb, Esp);
    k_split<<<(NB * 128) / 256, 256, 0, stream>>>(h2, Rsp, -32.f);

    for (int q = 0; q < 4; q++) {
        const float* R = (q == 0) ? h2 : rbuf;
        const float* Eq = cb + (size_t)q * 8192 * 128;
        const _Float16* EspQ = Esp + (size_t)q * 2097152;
        dim3 gq(NB / 128, 8);
        k_vq_argmin_mfma<<<gq, 512, 0, stream>>>(Rsp, EspQ, cbn + q * 8192, pbest, pidx);
        k_vq_reduce<<<NB / 256, 256, 0, stream>>>(pbest, pidx, idxb, ids_f + q);
        k_vq_update<<<(NB * 128) / 256, 256, 0, stream>>>(R, idxb, Eq, rbuf, qsum, vl,
                                                          q == 0 ? 1 : 0, Rsp);
    }

    // dec weight splits (rbuf dead after last vq_update)
    k_wsplit<<<(128 * 256) / 256, 256, 0, stream>>>(dec_w0, WtD0, 128, 256);
    k_wsplit<<<(256 * 512) / 256, 256, 0, stream>>>(dec_w1, WtD1, 256, 512);
    k_wsplit<<<(512 * 768) / 256, 256, 0, stream>>>(dec_w2, WtD2, 512, 768);

    k_mfma_rms<256><<<NB / 64, 512, 0, stream>>>(qsum, WtD0, dec_b0, dec_g0, h1, 128);
    k_mfma_rms<512><<<NB / 64, 512, 0, stream>>>(h1, WtD1, dec_b1, dec_g1, h0, 256);

    dim3 g2(NB / 64, 3);
    k_mfma_dec2<<<g2, 512, 0, stream>>>(h0, WtD2, dec_b2, xn, rl, 512);
}

// Round 4
// 1379.199 us; speedup vs baseline: 2.3606x; 1.0105x over previous
//
#include <hip/hip_runtime.h>
#include <math.h>

#define NB 16384
#define DIN 768

typedef _Float16 f16x8 __attribute__((ext_vector_type(8)));
typedef float f32x16 __attribute__((ext_vector_type(16)));

// ---------------- small kernels ----------------

__global__ void k_zero2(float* a, float* b) {
    if (threadIdx.x == 0) { *a = 0.f; *b = 0.f; }
}

__global__ void k_norm(const float* __restrict__ x, const float* __restrict__ m,
                       const float* __restrict__ s, float* __restrict__ xn) {
    int i = blockIdx.x * 256 + threadIdx.x;          // 16384*768 total
    int j = i % DIN;
    xn[i] = (x[i] - m[j]) / s[j];
}

// one 64-lane wave per codebook row; writes ||E||^2 * 4096 (r*-32, E*256 scaling)
__global__ void k_cbnorm(const float* __restrict__ cb, float* __restrict__ cbn) {
    int row = blockIdx.x * 4 + (threadIdx.x >> 6);
    int lane = threadIdx.x & 63;
    const float* p = cb + (size_t)row * 128;
    float v0 = p[lane], v1 = p[lane + 64];
    float s = v0 * v0 + v1 * v1;
    #pragma unroll
    for (int m = 32; m >= 1; m >>= 1) s += __shfl_xor(s, m, 64);
    if (lane == 0) cbn[row] = s * 4096.f;
}

// split fp32 rows (n x 128) into fp16 hi|lo layout (n x 256): [hi(128) | lo(128)]
__global__ void k_split(const float* __restrict__ src, _Float16* __restrict__ dst,
                        float scale) {
    int i = blockIdx.x * 256 + threadIdx.x;   // n*128 elements
    int row = i >> 7, d = i & 127;
    float v = src[i] * scale;
    _Float16 hi = (_Float16)v;
    dst[(size_t)row * 256 + d] = hi;
    dst[(size_t)row * 256 + 128 + d] = (_Float16)(v - (float)hi);
}

// E split into per-chunk granule layout (v3: 32-code chunks) consumed linearly
// by global_load_lds: chunk ch = c>>5; halfs offset =
//   q*2097152 + ch*8192 + slice*256 + (c&31)*8 + (k&7)
// slice = k>>3 (hi) / 16 + (k>>3) (lo). Scale 256.
__global__ void k_esplit(const float* __restrict__ cb, _Float16* __restrict__ Esp) {
    int i = blockIdx.x * 256 + threadIdx.x;   // 4*8192*128 total
    int q = i >> 20;
    int rem = i & 1048575;
    int c = rem >> 7, k = rem & 127;
    float v = cb[i] * 256.f;
    _Float16 hi = (_Float16)v;
    _Float16 lo = (_Float16)(v - (float)hi);
    int sh = k >> 3, j = k & 7;
    size_t base = (size_t)q * 2097152 + (size_t)(c >> 5) * 8192 + (size_t)(c & 31) * 8 + j;
    Esp[base + (size_t)sh * 256] = hi;
    Esp[base + (size_t)(16 + sh) * 256] = lo;
}

// ---------------- weight transpose-split into chunked granule layout ----------
// W (K x N fp32) -> Wt halfs, granule (kc, s, c): ((kc*8+s)*N + c)*8 + j
// k = kc*32 + t*16 + g*8 + j ; s = t*2+g (hi), 4+t*2+g (lo). Scale 256.
__global__ void k_wsplit(const float* __restrict__ W, _Float16* __restrict__ Wt,
                         int K, int N) {
    int i = blockIdx.x * 256 + threadIdx.x;   // K*N total
    int k = i / N, c = i - k * N;
    float v = W[i] * 256.f;
    _Float16 hi = (_Float16)v;
    _Float16 lo = (_Float16)(v - (float)hi);
    int kc = k >> 5, kin = k & 31;
    int t = kin >> 4, gg = (kin >> 3) & 1, j = kin & 7;
    size_t base = ((size_t)(kc * 8) * N + c) * 8 + j;
    Wt[base + (size_t)(t * 2 + gg) * N * 8] = hi;
    Wt[base + (size_t)(4 + t * 2 + gg) * N * 8] = lo;
}

// ---------------- fused MFMA Linear + ReLU + RMSNorm ----------------
// (unchanged, verified round 2)
template <int N>
__global__ __launch_bounds__(512, 2) void k_mfma_rms(
    const float* __restrict__ A, const _Float16* __restrict__ Wt,
    const float* __restrict__ bias, const float* __restrict__ g,
    float* __restrict__ out, int K) {
    constexpr int CT = N / 128;               // col-tiles per wave
    __shared__ __align__(16) _Float16 Bs[2][N * 64];
    __shared__ float ssbuf[64][4];
    const int tid = threadIdx.x;
    const int w = tid >> 6, lane = tid & 63;
    const int wr = w >> 2, wc = w & 3;
    const int g32 = lane >> 5, cl = lane & 31;
    const int row0 = blockIdx.x * 64;
    const int NC = K >> 5;                    // chunks of 32 k (always even)

    const float* ap = A + (size_t)(row0 + wr * 32 + cl) * K + g32 * 8;

    f32x16 acc[CT];
    #pragma unroll
    for (int tt = 0; tt < CT; tt++)
        #pragma unroll
        for (int m = 0; m < 16; m++) acc[tt][m] = 0.f;

    float4 Ar0[4], Ar1[4];

    auto STAGE = [&](int ch, int b) {
        const _Float16* gp = Wt + (size_t)ch * 8 * N * 8;
        #pragma unroll
        for (int p = 0; p < N / 64; p++) {
            int f = tid + 512 * p;
            __builtin_amdgcn_global_load_lds(
                (const __attribute__((address_space(1))) void*)(gp + (size_t)f * 8),
                (__attribute__((address_space(3))) void*)(&Bs[b][(size_t)f * 8]),
                16, 0, 0);
        }
    };
    auto AISSUE = [&](int ch, float4* Ar) {
        const float* bsrc = ap + ch * 32;
        Ar[0] = *(const float4*)(bsrc);
        Ar[1] = *(const float4*)(bsrc + 4);
        Ar[2] = *(const float4*)(bsrc + 16);
        Ar[3] = *(const float4*)(bsrc + 20);
    };
    auto COMPUTE = [&](int b, const float4* Ar) {
        #pragma unroll
        for (int t = 0; t < 2; t++) {
            float vv[8] = {Ar[t * 2].x, Ar[t * 2].y, Ar[t * 2].z, Ar[t * 2].w,
                           Ar[t * 2 + 1].x, Ar[t * 2 + 1].y, Ar[t * 2 + 1].z, Ar[t * 2 + 1].w};
            f16x8 ah, al;
            #pragma unroll
            for (int j = 0; j < 8; j++) {
                float v = vv[j] * 16.f;
                _Float16 h = (_Float16)v;
                ah[j] = h;
                al[j] = (_Float16)(v - (float)h);
            }
            #pragma unroll
            for (int tt = 0; tt < CT; tt++) {
                int c = wc * (N / 4) + tt * 32 + cl;
                f16x8 bh = *(const f16x8*)&Bs[b][((size_t)(t * 2 + g32) * N + c) * 8];
                f16x8 bl = *(const f16x8*)&Bs[b][((size_t)(4 + t * 2 + g32) * N + c) * 8];
                acc[tt] = __builtin_amdgcn_mfma_f32_32x32x16_f16(ah, bh, acc[tt], 0, 0, 0);
                acc[tt] = __builtin_amdgcn_mfma_f32_32x32x16_f16(al, bh, acc[tt], 0, 0, 0);
                acc[tt] = __builtin_amdgcn_mfma_f32_32x32x16_f16(ah, bl, acc[tt], 0, 0, 0);
            }
        }
    };

    AISSUE(0, Ar0);
    STAGE(0, 0);
    for (int ch = 0; ch < NC; ch += 2) {
        __syncthreads();                      // drains stage(ch) + A loads
        STAGE(ch + 1, 1);
        AISSUE(ch + 1, Ar1);
        COMPUTE(0, Ar0);
        __syncthreads();                      // drains stage(ch+1)
        if (ch + 2 < NC) { STAGE(ch + 2, 0); AISSUE(ch + 2, Ar0); }
        COMPUTE(1, Ar1);
    }

    // epilogue: /4096 + bias + relu + rmsnorm
    constexpr float INV = 1.f / 4096.f;
    float bb[CT], gv[CT];
    #pragma unroll
    for (int tt = 0; tt < CT; tt++) {
        int c = wc * (N / 4) + tt * 32 + cl;
        bb[tt] = bias[c];
        gv[tt] = g[c];
    }
    float ssm[16];
    #pragma unroll
    for (int m = 0; m < 16; m++) ssm[m] = 0.f;
    #pragma unroll
    for (int tt = 0; tt < CT; tt++)
        #pragma unroll
        for (int m = 0; m < 16; m++) {
            float v = fmaf(acc[tt][m], INV, bb[tt]);
            v = v > 0.f ? v : 0.f;
            acc[tt][m] = v;
            ssm[m] = fmaf(v, v, ssm[m]);
        }
    #pragma unroll
    for (int mask = 1; mask < 32; mask <<= 1)
        #pragma unroll
        for (int m = 0; m < 16; m++) ssm[m] += __shfl_xor(ssm[m], mask, 64);
    if (cl == 0) {
        #pragma unroll
        for (int m = 0; m < 16; m++) {
            int rl = wr * 32 + (m & 3) + 8 * (m >> 2) + 4 * g32;
            ssbuf[rl][wc] = ssm[m];
        }
    }
    __syncthreads();
    #pragma unroll
    for (int m = 0; m < 16; m++) {
        int rl = wr * 32 + (m & 3) + 8 * (m >> 2) + 4 * g32;
        float s4 = (ssbuf[rl][0] + ssbuf[rl][1]) + (ssbuf[rl][2] + ssbuf[rl][3]);
        float sc = 1.0f / sqrtf(s4 * (1.0f / (float)N) + 1e-6f);
        #pragma unroll
        for (int tt = 0; tt < CT; tt++) {
            int c = wc * (N / 4) + tt * 32 + cl;
            out[(size_t)(row0 + rl) * N + c] = acc[tt][m] * sc * gv[tt];
        }
    }
}

// ---------------- final MFMA Linear (512->768) + recon loss ----------------
// (unchanged, verified round 2)
__global__ __launch_bounds__(512, 2) void k_mfma_dec2(
    const float* __restrict__ A, const _Float16* __restrict__ Wt,
    const float* __restrict__ bias, float* __restrict__ rec,
    float* __restrict__ loss_acc, int K) {
    constexpr int NT = 256, NF = 768, CT = 2;
    __shared__ __align__(16) _Float16 Bs[2][NT * 64];
    __shared__ float red[8];
    const int tid = threadIdx.x;
    const int w = tid >> 6, lane = tid & 63;
    const int wr = w >> 2, wc = w & 3;
    const int g32 = lane >> 5, cl = lane & 31;
    const int row0 = blockIdx.x * 64;
    const int col0 = blockIdx.y * NT;
    const int NC = K >> 5;

    const float* ap = A + (size_t)(row0 + wr * 32 + cl) * K + g32 * 8;

    f32x16 acc[CT];
    #pragma unroll
    for (int tt = 0; tt < CT; tt++)
        #pragma unroll
        for (int m = 0; m < 16; m++) acc[tt][m] = 0.f;

    float4 Ar0[4], Ar1[4];

    auto STAGE = [&](int ch, int b) {
        #pragma unroll
        for (int p = 0; p < 4; p++) {
            int f = tid + 512 * p;
            int s = f >> 8, cloc = f & 255;
            const _Float16* gp = Wt + ((size_t)(ch * 8 + s) * NF + col0 + cloc) * 8;
            __builtin_amdgcn_global_load_lds(
                (const __attribute__((address_space(1))) void*)gp,
                (__attribute__((address_space(3))) void*)(&Bs[b][(size_t)f * 8]),
                16, 0, 0);
        }
    };
    auto AISSUE = [&](int ch, float4* Ar) {
        const float* bsrc = ap + ch * 32;
        Ar[0] = *(const float4*)(bsrc);
        Ar[1] = *(const float4*)(bsrc + 4);
        Ar[2] = *(const float4*)(bsrc + 16);
        Ar[3] = *(const float4*)(bsrc + 20);
    };
    auto COMPUTE = [&](int b, const float4* Ar) {
        #pragma unroll
        for (int t = 0; t < 2; t++) {
            float vv[8] = {Ar[t * 2].x, Ar[t * 2].y, Ar[t * 2].z, Ar[t * 2].w,
                           Ar[t * 2 + 1].x, Ar[t * 2 + 1].y, Ar[t * 2 + 1].z, Ar[t * 2 + 1].w};
            f16x8 ah, al;
            #pragma unroll
            for (int j = 0; j < 8; j++) {
                float v = vv[j] * 16.f;
                _Float16 h = (_Float16)v;
                ah[j] = h;
                al[j] = (_Float16)(v - (float)h);
            }
            #pragma unroll
            for (int tt = 0; tt < CT; tt++) {
                int c = wc * 64 + tt * 32 + cl;
                f16x8 bh = *(const f16x8*)&Bs[b][((size_t)(t * 2 + g32) * NT + c) * 8];
                f16x8 bl = *(const f16x8*)&Bs[b][((size_t)(4 + t * 2 + g32) * NT + c) * 8];
                acc[tt] = __builtin_amdgcn_mfma_f32_32x32x16_f16(ah, bh, acc[tt], 0, 0, 0);
                acc[tt] = __builtin_amdgcn_mfma_f32_32x32x16_f16(al, bh, acc[tt], 0, 0, 0);
                acc[tt] = __builtin_amdgcn_mfma_f32_32x32x16_f16(ah, bl, acc[tt], 0, 0, 0);
            }
        }
    };

    AISSUE(0, Ar0);
    STAGE(0, 0);
    for (int ch = 0; ch < NC; ch += 2) {
        __syncthreads();
        STAGE(ch + 1, 1);
        AISSUE(ch + 1, Ar1);
        COMPUTE(0, Ar0);
        __syncthreads();
        if (ch + 2 < NC) { STAGE(ch + 2, 0); AISSUE(ch + 2, Ar0); }
        COMPUTE(1, Ar1);
    }

    constexpr float INV = 1.f / 4096.f;
    float lsum = 0.f;
    #pragma unroll
    for (int tt = 0; tt < CT; tt++) {
        int cg = col0 + wc * 64 + tt * 32 + cl;
        float bb = bias[cg];
        #pragma unroll
        for (int m = 0; m < 16; m++) {
            int rl = wr * 32 + (m & 3) + 8 * (m >> 2) + 4 * g32;
            float v = fmaf(acc[tt][m], INV, bb);
            size_t o = (size_t)(row0 + rl) * NF + cg;
            float e = v - rec[o];             // rec holds xn here
            lsum = fmaf(e, e, lsum);
            rec[o] = v;
        }
    }
    #pragma unroll
    for (int mask = 1; mask < 64; mask <<= 1) lsum += __shfl_xor(lsum, mask, 64);
    if (lane == 0) red[w] = lsum;
    __syncthreads();
    if (tid == 0) {
        float t = 0.f;
        #pragma unroll
        for (int i = 0; i < 8; i++) t += red[i];
        atomicAdd(loss_acc, t * (1.0f / ((float)NB * (float)DIN)));
    }
}

// ---------------- VQ: fp16 hi/lo split MFMA scores + partial argmin (v3) -----
// score = 4096||E||^2 + (-32 r)·(256 E)  (-2 folded into R scale)
// v3: residency-first geometry. grid (NB/256, 16 strips of 512 codes);
// block 512 thr = 8 row-group waves (32 rows each, 256 rows/block), all waves
// share each 32-code chunk. LDS 2 x 16KB (was 2 x 32KB) -> 2-3 blocks/CU
// co-resident to fill barrier-drain bubbles (was 1 block/CU, occupancy 21%).
// Esp granule pre-arranged per 32-code chunk -> staging = linear
// global_load_lds, ONE barrier per chunk. Frag reads contiguous 512B/32-lane
// group -> conflict-free. 2 acc chains; setprio(1) around MFMA cluster (T5).
__global__ __launch_bounds__(512, 2) void k_vq_argmin_mfma(
    const _Float16* __restrict__ Rsp, const _Float16* __restrict__ Esp,
    const float* __restrict__ cbnS,
    float* __restrict__ pbest, int* __restrict__ pidx) {
    __shared__ __align__(16) _Float16 Es[2][8192];    // 2 x 16KB
    const int tid = threadIdx.x;
    const int w = tid >> 6, lane = tid & 63;
    const int g = lane >> 5, cl31 = lane & 31;
    const int row0 = blockIdx.x * 256 + w * 32;
    const int cbase = blockIdx.y * 512;
    const int ch0 = blockIdx.y * 16;

    // A fragments: row = row0 + (lane&31), k = kc*16 + g*8 + j (verified map)
    f16x8 Ah[8], Al[8];
    {
        const _Float16* rp = Rsp + (size_t)(row0 + cl31) * 256 + g * 8;
        #pragma unroll
        for (int kc = 0; kc < 8; kc++) {
            Ah[kc] = *(const f16x8*)(rp + kc * 16);
            Al[kc] = *(const f16x8*)(rp + 128 + kc * 16);
        }
    }

    float best[16];
    int bidx[16];
    #pragma unroll
    for (int m = 0; m < 16; m++) { best[m] = 3.402823466e+38f; bidx[m] = 0; }

    auto STAGE = [&](int gch, int b) {
        const _Float16* gp = Esp + (size_t)gch * 8192;
        #pragma unroll
        for (int p = 0; p < 2; p++) {
            int f = tid + 512 * p;
            __builtin_amdgcn_global_load_lds(
                (const __attribute__((address_space(1))) void*)(gp + (size_t)f * 8),
                (__attribute__((address_space(3))) void*)(&Es[b][(size_t)f * 8]),
                16, 0, 0);
        }
    };

    STAGE(ch0, 0);
    for (int ch = 0; ch < 16; ch++) {
        const int buf = ch & 1;
        __syncthreads();                      // stage(ch) landed; buf free to read
        if (ch < 15) STAGE(ch0 + ch + 1, buf ^ 1);
        int c = cbase + ch * 32 + cl31;
        float cn = cbnS[c];
        f32x16 a0, a1;
        #pragma unroll
        for (int m = 0; m < 16; m++) { a0[m] = 0.f; a1[m] = 0.f; }
        __builtin_amdgcn_s_setprio(1);
        #pragma unroll
        for (int kc = 0; kc < 8; kc++) {
            int sh = kc * 2 + g;
            f16x8 bh = *(const f16x8*)&Es[buf][sh * 256 + cl31 * 8];
            f16x8 bl = *(const f16x8*)&Es[buf][(16 + sh) * 256 + cl31 * 8];
            a0 = __builtin_amdgcn_mfma_f32_32x32x16_f16(Ah[kc], bh, a0, 0, 0, 0);
            a0 = __builtin_amdgcn_mfma_f32_32x32x16_f16(Al[kc], bh, a0, 0, 0, 0);
            a1 = __builtin_amdgcn_mfma_f32_32x32x16_f16(Ah[kc], bl, a1, 0, 0, 0);
        }
        __builtin_amdgcn_s_setprio(0);
        // running argmin; codes ascending per thread -> strict < keeps first
        #pragma unroll
        for (int m = 0; m < 16; m++) {
            float s = (a0[m] + a1[m]) + cn;
            if (s < best[m]) { best[m] = s; bidx[m] = c; }
        }
    }

    // reduce across 32 code-lanes (xor masks < 32 stay within lane-half);
    // tie -> smaller index (numpy first-occurrence)
    #pragma unroll
    for (int mask = 1; mask < 32; mask <<= 1) {
        #pragma unroll
        for (int m = 0; m < 16; m++) {
            float ob = __shfl_xor(best[m], mask, 64);
            int oi = __shfl_xor(bidx[m], mask, 64);
            if (ob < best[m] || (ob == best[m] && oi < bidx[m])) { best[m] = ob; bidx[m] = oi; }
        }
    }
    if (cl31 == 0) {
        int part = blockIdx.y;
        // C/D layout (m74): row = (reg&3) + 8*(reg>>2) + 4*(lane>>5)
        #pragma unroll
        for (int m = 0; m < 16; m++) {
            int row = row0 + (m & 3) + 8 * (m >> 2) + 4 * g;
            pbest[(size_t)part * NB + row] = best[m];
            pidx[(size_t)part * NB + row] = bidx[m];
        }
    }
}

// merge the 16 strip-partials; tie -> smaller index
__global__ void k_vq_reduce(const float* __restrict__ pbest, const int* __restrict__ pidx,
                            int* __restrict__ idx_out, float* __restrict__ ids_f) {
    int row = blockIdx.x * 256 + threadIdx.x;
    float b = pbest[row];
    int bi = pidx[row];
    #pragma unroll
    for (int s = 1; s < 16; s++) {
        float ob = pbest[(size_t)s * NB + row];
        int oi = pidx[(size_t)s * NB + row];
        if (ob < b || (ob == b && oi < bi)) { b = ob; bi = oi; }
    }
    idx_out[row] = bi;
    ids_f[(size_t)row * 4] = (float)bi;
}

// gather + residual update + qsum + vq_loss partial; writes fp16 split (x -32)
__global__ void k_vq_update(const float* __restrict__ Rin, const int* __restrict__ idx,
                            const float* __restrict__ E, float* __restrict__ Rout,
                            float* __restrict__ qsum, float* __restrict__ vq_acc,
                            int firstq, _Float16* __restrict__ Rsp) {
    __shared__ float ps[4];
    int i = blockIdx.x * 256 + threadIdx.x;   // NB*128 total
    int row = i >> 7, d = i & 127;
    float e = E[(size_t)idx[row] * 128 + d];
    float rv = Rin[i] - e;
    Rout[i] = rv;
    qsum[i] = firstq ? e : (qsum[i] + e);
    float rs = rv * -32.f;
    _Float16 hi = (_Float16)rs;
    Rsp[(size_t)row * 256 + d] = hi;
    Rsp[(size_t)row * 256 + 128 + d] = (_Float16)(rs - (float)hi);
    float p = rv * rv;
    #pragma unroll
    for (int m = 1; m < 64; m <<= 1) p += __shfl_xor(p, m, 64);
    int lane = threadIdx.x & 63, wv = threadIdx.x >> 6;
    if (lane == 0) ps[wv] = p;
    __syncthreads();
    if (threadIdx.x == 0)
        atomicAdd(vq_acc, (ps[0] + ps[1] + ps[2] + ps[3]) * (1.25f / ((float)NB * 128.f)));
}

// ---------------- launch ----------------

extern "C" void kernel_launch(void* const* d_in, const int* in_sizes, int n_in,
                              void* d_out, int out_size, void* d_ws, size_t ws_size,
                              hipStream_t stream) {
    (void)in_sizes; (void)n_in; (void)out_size; (void)ws_size;
    const float* x        = (const float*)d_in[0];
    const float* emb_mean = (const float*)d_in[1];
    const float* emb_std  = (const float*)d_in[2];
    const float* enc_w0 = (const float*)d_in[3];
    const float* enc_b0 = (const float*)d_in[4];
    const float* enc_g0 = (const float*)d_in[5];
    const float* enc_w1 = (const float*)d_in[6];
    const float* enc_b1 = (const float*)d_in[7];
    const float* enc_g1 = (const float*)d_in[8];
    const float* enc_w2 = (const float*)d_in[9];
    const float* enc_b2 = (const float*)d_in[10];
    const float* enc_g2 = (const float*)d_in[11];
    const float* cb     = (const float*)d_in[12];
    const float* dec_w0 = (const float*)d_in[13];
    const float* dec_b0 = (const float*)d_in[14];
    const float* dec_g0 = (const float*)d_in[15];
    const float* dec_w1 = (const float*)d_in[16];
    const float* dec_b1 = (const float*)d_in[17];
    const float* dec_g1 = (const float*)d_in[18];
    const float* dec_w2 = (const float*)d_in[19];
    const float* dec_b2 = (const float*)d_in[20];

    float* out   = (float*)d_out;
    float* xn    = out;                        // recon region doubles as xn scratch
    float* ids_f = out + (size_t)NB * DIN;
    float* rl    = out + (size_t)NB * DIN + (size_t)NB * 4;
    float* vl    = rl + 1;

    float* ws   = (float*)d_ws;
    float* h0   = ws;                           // 16384*512
    float* h1   = h0 + (size_t)NB * 512;        // 16384*256
    float* h2   = h1 + (size_t)NB * 256;        // 16384*128
    float* rbuf = h2 + (size_t)NB * 128;        // 16384*128
    float* qsum = rbuf + (size_t)NB * 128;      // 16384*128
    float* cbn  = qsum + (size_t)NB * 128;      // 4*8192
    int*   idxb = (int*)(cbn + 4 * 8192);       // 16384

    // VQ scratch in h0 (free between enc1-read and dec1-write):
    //   pbest 16*NB f, pidx 16*NB i, Rsp NB*256 halfs, Esp 4*8192*256 halfs
    //   = 0.52M + 2.10M + 4.19M float-equiv = 6.82M < 8.39M.
    float*    pbest = h0;                                   // 16*16384
    int*      pidx  = (int*)(h0 + 16 * (size_t)NB);         // 16*16384
    _Float16* Rsp   = (_Float16*)(h0 + 32 * (size_t)NB);
    _Float16* Esp   = (_Float16*)(h0 + 32 * (size_t)NB + (size_t)NB * 128);

    // weight splits live in rbuf: enc set dead before VQ writes rbuf (q=0
    // update); dec set written after the last vq_update reads rbuf.
    _Float16* WtE0 = (_Float16*)rbuf;           // 768*512*2 = 786432 halfs
    _Float16* WtE1 = WtE0 + 786432;             // 512*256*2 = 262144
    _Float16* WtE2 = WtE0 + 1048576;            // 256*128*2 =  65536
    _Float16* WtD0 = (_Float16*)rbuf;           // 128*256*2 =  65536
    _Float16* WtD1 = WtD0 + 65536;              // 256*512*2 = 262144
    _Float16* WtD2 = WtD0 + 327680;             // 512*768*2 = 786432

    k_zero2<<<1, 64, 0, stream>>>(rl, vl);
    k_norm<<<(NB * DIN) / 256, 256, 0, stream>>>(x, emb_mean, emb_std, xn);
    k_cbnorm<<<(4 * 8192) / 4, 256, 0, stream>>>(cb, cbn);

    k_wsplit<<<(768 * 512) / 256, 256, 0, stream>>>(enc_w0, WtE0, 768, 512);
    k_wsplit<<<(512 * 256) / 256, 256, 0, stream>>>(enc_w1, WtE1, 512, 256);
    k_wsplit<<<(256 * 128) / 256, 256, 0, stream>>>(enc_w2, WtE2, 256, 128);

    k_mfma_rms<512><<<NB / 64, 512, 0, stream>>>(xn, WtE0, enc_b0, enc_g0, h0, 768);
    k_mfma_rms<256><<<NB / 64, 512, 0, stream>>>(h0, WtE1, enc_b1, enc_g1, h1, 512);
    k_mfma_rms<128><<<NB / 64, 512, 0, stream>>>(h1, WtE2, enc_b2, enc_g2, h2, 256);

    // fp16 splits for VQ (into h0 region, after enc1 consumed h0)
    k_esplit<<<(4 * 8192 * 128) / 256, 256, 0, stream>>>(cb, Esp);
    k_split<<<(NB * 128) / 256, 256, 0, stream>>>(h2, Rsp, -32.f);

    for (int q = 0; q < 4; q++) {
        const float* R = (q == 0) ? h2 : rbuf;
        const float* Eq = cb + (size_t)q * 8192 * 128;
        const _Float16* EspQ = Esp + (size_t)q * 2097152;
        dim3 gq(NB / 256, 16);
        k_vq_argmin_mfma<<<gq, 512, 0, stream>>>(Rsp, EspQ, cbn + q * 8192, pbest, pidx);
        k_vq_reduce<<<NB / 256, 256, 0, stream>>>(pbest, pidx, idxb, ids_f + q);
        k_vq_update<<<(NB * 128) / 256, 256, 0, stream>>>(R, idxb, Eq, rbuf, qsum, vl,
                                                          q == 0 ? 1 : 0, Rsp);
    }

    // dec weight splits (rbuf dead after last vq_update)
    k_wsplit<<<(128 * 256) / 256, 256, 0, stream>>>(dec_w0, WtD0, 128, 256);
    k_wsplit<<<(256 * 512) / 256, 256, 0, stream>>>(dec_w1, WtD1, 256, 512);
    k_wsplit<<<(512 * 768) / 256, 256, 0, stream>>>(dec_w2, WtD2, 512, 768);

    k_mfma_rms<256><<<NB / 64, 512, 0, stream>>>(qsum, WtD0, dec_b0, dec_g0, h1, 128);
    k_mfma_rms<512><<<NB / 64, 512, 0, stream>>>(h1, WtD1, dec_b1, dec_g1, h0, 256);

    dim3 g2(NB / 64, 3);
    k_mfma_dec2<<<g2, 512, 0, stream>>>(h0, WtD2, dec_b2, xn, rl, 512);
}

// Round 5
// 1254.483 us; speedup vs baseline: 2.5952x; 1.0994x over previous
//
#include <hip/hip_runtime.h>
#include <math.h>

#define NB 16384
#define DIN 768

typedef _Float16 f16x8 __attribute__((ext_vector_type(8)));
typedef float f32x16 __attribute__((ext_vector_type(16)));

// ---------------- small kernels ----------------

__global__ void k_zero2(float* a, float* b) {
    if (threadIdx.x == 0) { *a = 0.f; *b = 0.f; }
}

__global__ void k_norm(const float* __restrict__ x, const float* __restrict__ m,
                       const float* __restrict__ s, float* __restrict__ xn) {
    int i = blockIdx.x * 256 + threadIdx.x;          // 16384*768 total
    int j = i % DIN;
    xn[i] = (x[i] - m[j]) / s[j];
}

// one 64-lane wave per codebook row; writes ||E||^2 * 4096 (r*-32, E*256 scaling)
__global__ void k_cbnorm(const float* __restrict__ cb, float* __restrict__ cbn) {
    int row = blockIdx.x * 4 + (threadIdx.x >> 6);
    int lane = threadIdx.x & 63;
    const float* p = cb + (size_t)row * 128;
    float v0 = p[lane], v1 = p[lane + 64];
    float s = v0 * v0 + v1 * v1;
    #pragma unroll
    for (int m = 32; m >= 1; m >>= 1) s += __shfl_xor(s, m, 64);
    if (lane == 0) cbn[row] = s * 4096.f;
}

// split fp32 rows (n x 128) into fp16 hi|lo layout (n x 256): [hi(128) | lo(128)]
__global__ void k_split(const float* __restrict__ src, _Float16* __restrict__ dst,
                        float scale) {
    int i = blockIdx.x * 256 + threadIdx.x;   // n*128 elements
    int row = i >> 7, d = i & 127;
    float v = src[i] * scale;
    _Float16 hi = (_Float16)v;
    dst[(size_t)row * 256 + d] = hi;
    dst[(size_t)row * 256 + 128 + d] = (_Float16)(v - (float)hi);
}

// E split into per-chunk granule layout (32-code chunks) consumed linearly
// by global_load_lds: chunk ch = c>>5; halfs offset =
//   q*2097152 + ch*8192 + slice*256 + (c&31)*8 + (k&7)
// slice = k>>3 (hi) / 16 + (k>>3) (lo). Scale 256.
__global__ void k_esplit(const float* __restrict__ cb, _Float16* __restrict__ Esp) {
    int i = blockIdx.x * 256 + threadIdx.x;   // 4*8192*128 total
    int q = i >> 20;
    int rem = i & 1048575;
    int c = rem >> 7, k = rem & 127;
    float v = cb[i] * 256.f;
    _Float16 hi = (_Float16)v;
    _Float16 lo = (_Float16)(v - (float)hi);
    int sh = k >> 3, j = k & 7;
    size_t base = (size_t)q * 2097152 + (size_t)(c >> 5) * 8192 + (size_t)(c & 31) * 8 + j;
    Esp[base + (size_t)sh * 256] = hi;
    Esp[base + (size_t)(16 + sh) * 256] = lo;
}

// ---------------- weight transpose-split into chunked granule layout ----------
// W (K x N fp32) -> Wt halfs, granule (kc, s, c): ((kc*8+s)*N + c)*8 + j
// k = kc*32 + t*16 + g*8 + j ; s = t*2+g (hi), 4+t*2+g (lo). Scale 256.
__global__ void k_wsplit(const float* __restrict__ W, _Float16* __restrict__ Wt,
                         int K, int N) {
    int i = blockIdx.x * 256 + threadIdx.x;   // K*N total
    int k = i / N, c = i - k * N;
    float v = W[i] * 256.f;
    _Float16 hi = (_Float16)v;
    _Float16 lo = (_Float16)(v - (float)hi);
    int kc = k >> 5, kin = k & 31;
    int t = kin >> 4, gg = (kin >> 3) & 1, j = kin & 7;
    size_t base = ((size_t)(kc * 8) * N + c) * 8 + j;
    Wt[base + (size_t)(t * 2 + gg) * N * 8] = hi;
    Wt[base + (size_t)(4 + t * 2 + gg) * N * 8] = lo;
}

// ---------------- fused MFMA Linear + ReLU + RMSNorm ----------------
// (unchanged, verified round 2)
template <int N>
__global__ __launch_bounds__(512, 2) void k_mfma_rms(
    const float* __restrict__ A, const _Float16* __restrict__ Wt,
    const float* __restrict__ bias, const float* __restrict__ g,
    float* __restrict__ out, int K) {
    constexpr int CT = N / 128;               // col-tiles per wave
    __shared__ __align__(16) _Float16 Bs[2][N * 64];
    __shared__ float ssbuf[64][4];
    const int tid = threadIdx.x;
    const int w = tid >> 6, lane = tid & 63;
    const int wr = w >> 2, wc = w & 3;
    const int g32 = lane >> 5, cl = lane & 31;
    const int row0 = blockIdx.x * 64;
    const int NC = K >> 5;                    // chunks of 32 k (always even)

    const float* ap = A + (size_t)(row0 + wr * 32 + cl) * K + g32 * 8;

    f32x16 acc[CT];
    #pragma unroll
    for (int tt = 0; tt < CT; tt++)
        #pragma unroll
        for (int m = 0; m < 16; m++) acc[tt][m] = 0.f;

    float4 Ar0[4], Ar1[4];

    auto STAGE = [&](int ch, int b) {
        const _Float16* gp = Wt + (size_t)ch * 8 * N * 8;
        #pragma unroll
        for (int p = 0; p < N / 64; p++) {
            int f = tid + 512 * p;
            __builtin_amdgcn_global_load_lds(
                (const __attribute__((address_space(1))) void*)(gp + (size_t)f * 8),
                (__attribute__((address_space(3))) void*)(&Bs[b][(size_t)f * 8]),
                16, 0, 0);
        }
    };
    auto AISSUE = [&](int ch, float4* Ar) {
        const float* bsrc = ap + ch * 32;
        Ar[0] = *(const float4*)(bsrc);
        Ar[1] = *(const float4*)(bsrc + 4);
        Ar[2] = *(const float4*)(bsrc + 16);
        Ar[3] = *(const float4*)(bsrc + 20);
    };
    auto COMPUTE = [&](int b, const float4* Ar) {
        #pragma unroll
        for (int t = 0; t < 2; t++) {
            float vv[8] = {Ar[t * 2].x, Ar[t * 2].y, Ar[t * 2].z, Ar[t * 2].w,
                           Ar[t * 2 + 1].x, Ar[t * 2 + 1].y, Ar[t * 2 + 1].z, Ar[t * 2 + 1].w};
            f16x8 ah, al;
            #pragma unroll
            for (int j = 0; j < 8; j++) {
                float v = vv[j] * 16.f;
                _Float16 h = (_Float16)v;
                ah[j] = h;
                al[j] = (_Float16)(v - (float)h);
            }
            #pragma unroll
            for (int tt = 0; tt < CT; tt++) {
                int c = wc * (N / 4) + tt * 32 + cl;
                f16x8 bh = *(const f16x8*)&Bs[b][((size_t)(t * 2 + g32) * N + c) * 8];
                f16x8 bl = *(const f16x8*)&Bs[b][((size_t)(4 + t * 2 + g32) * N + c) * 8];
                acc[tt] = __builtin_amdgcn_mfma_f32_32x32x16_f16(ah, bh, acc[tt], 0, 0, 0);
                acc[tt] = __builtin_amdgcn_mfma_f32_32x32x16_f16(al, bh, acc[tt], 0, 0, 0);
                acc[tt] = __builtin_amdgcn_mfma_f32_32x32x16_f16(ah, bl, acc[tt], 0, 0, 0);
            }
        }
    };

    AISSUE(0, Ar0);
    STAGE(0, 0);
    for (int ch = 0; ch < NC; ch += 2) {
        __syncthreads();                      // drains stage(ch) + A loads
        STAGE(ch + 1, 1);
        AISSUE(ch + 1, Ar1);
        COMPUTE(0, Ar0);
        __syncthreads();                      // drains stage(ch+1)
        if (ch + 2 < NC) { STAGE(ch + 2, 0); AISSUE(ch + 2, Ar0); }
        COMPUTE(1, Ar1);
    }

    // epilogue: /4096 + bias + relu + rmsnorm
    constexpr float INV = 1.f / 4096.f;
    float bb[CT], gv[CT];
    #pragma unroll
    for (int tt = 0; tt < CT; tt++) {
        int c = wc * (N / 4) + tt * 32 + cl;
        bb[tt] = bias[c];
        gv[tt] = g[c];
    }
    float ssm[16];
    #pragma unroll
    for (int m = 0; m < 16; m++) ssm[m] = 0.f;
    #pragma unroll
    for (int tt = 0; tt < CT; tt++)
        #pragma unroll
        for (int m = 0; m < 16; m++) {
            float v = fmaf(acc[tt][m], INV, bb[tt]);
            v = v > 0.f ? v : 0.f;
            acc[tt][m] = v;
            ssm[m] = fmaf(v, v, ssm[m]);
        }
    #pragma unroll
    for (int mask = 1; mask < 32; mask <<= 1)
        #pragma unroll
        for (int m = 0; m < 16; m++) ssm[m] += __shfl_xor(ssm[m], mask, 64);
    if (cl == 0) {
        #pragma unroll
        for (int m = 0; m < 16; m++) {
            int rl = wr * 32 + (m & 3) + 8 * (m >> 2) + 4 * g32;
            ssbuf[rl][wc] = ssm[m];
        }
    }
    __syncthreads();
    #pragma unroll
    for (int m = 0; m < 16; m++) {
        int rl = wr * 32 + (m & 3) + 8 * (m >> 2) + 4 * g32;
        float s4 = (ssbuf[rl][0] + ssbuf[rl][1]) + (ssbuf[rl][2] + ssbuf[rl][3]);
        float sc = 1.0f / sqrtf(s4 * (1.0f / (float)N) + 1e-6f);
        #pragma unroll
        for (int tt = 0; tt < CT; tt++) {
            int c = wc * (N / 4) + tt * 32 + cl;
            out[(size_t)(row0 + rl) * N + c] = acc[tt][m] * sc * gv[tt];
        }
    }
}

// ---------------- final MFMA Linear (512->768) + recon loss ----------------
// (unchanged, verified round 2)
__global__ __launch_bounds__(512, 2) void k_mfma_dec2(
    const float* __restrict__ A, const _Float16* __restrict__ Wt,
    const float* __restrict__ bias, float* __restrict__ rec,
    float* __restrict__ loss_acc, int K) {
    constexpr int NT = 256, NF = 768, CT = 2;
    __shared__ __align__(16) _Float16 Bs[2][NT * 64];
    __shared__ float red[8];
    const int tid = threadIdx.x;
    const int w = tid >> 6, lane = tid & 63;
    const int wr = w >> 2, wc = w & 3;
    const int g32 = lane >> 5, cl = lane & 31;
    const int row0 = blockIdx.x * 64;
    const int col0 = blockIdx.y * NT;
    const int NC = K >> 5;

    const float* ap = A + (size_t)(row0 + wr * 32 + cl) * K + g32 * 8;

    f32x16 acc[CT];
    #pragma unroll
    for (int tt = 0; tt < CT; tt++)
        #pragma unroll
        for (int m = 0; m < 16; m++) acc[tt][m] = 0.f;

    float4 Ar0[4], Ar1[4];

    auto STAGE = [&](int ch, int b) {
        #pragma unroll
        for (int p = 0; p < 4; p++) {
            int f = tid + 512 * p;
            int s = f >> 8, cloc = f & 255;
            const _Float16* gp = Wt + ((size_t)(ch * 8 + s) * NF + col0 + cloc) * 8;
            __builtin_amdgcn_global_load_lds(
                (const __attribute__((address_space(1))) void*)gp,
                (__attribute__((address_space(3))) void*)(&Bs[b][(size_t)f * 8]),
                16, 0, 0);
        }
    };
    auto AISSUE = [&](int ch, float4* Ar) {
        const float* bsrc = ap + ch * 32;
        Ar[0] = *(const float4*)(bsrc);
        Ar[1] = *(const float4*)(bsrc + 4);
        Ar[2] = *(const float4*)(bsrc + 16);
        Ar[3] = *(const float4*)(bsrc + 20);
    };
    auto COMPUTE = [&](int b, const float4* Ar) {
        #pragma unroll
        for (int t = 0; t < 2; t++) {
            float vv[8] = {Ar[t * 2].x, Ar[t * 2].y, Ar[t * 2].z, Ar[t * 2].w,
                           Ar[t * 2 + 1].x, Ar[t * 2 + 1].y, Ar[t * 2 + 1].z, Ar[t * 2 + 1].w};
            f16x8 ah, al;
            #pragma unroll
            for (int j = 0; j < 8; j++) {
                float v = vv[j] * 16.f;
                _Float16 h = (_Float16)v;
                ah[j] = h;
                al[j] = (_Float16)(v - (float)h);
            }
            #pragma unroll
            for (int tt = 0; tt < CT; tt++) {
                int c = wc * 64 + tt * 32 + cl;
                f16x8 bh = *(const f16x8*)&Bs[b][((size_t)(t * 2 + g32) * NT + c) * 8];
                f16x8 bl = *(const f16x8*)&Bs[b][((size_t)(4 + t * 2 + g32) * NT + c) * 8];
                acc[tt] = __builtin_amdgcn_mfma_f32_32x32x16_f16(ah, bh, acc[tt], 0, 0, 0);
                acc[tt] = __builtin_amdgcn_mfma_f32_32x32x16_f16(al, bh, acc[tt], 0, 0, 0);
                acc[tt] = __builtin_amdgcn_mfma_f32_32x32x16_f16(ah, bl, acc[tt], 0, 0, 0);
            }
        }
    };

    AISSUE(0, Ar0);
    STAGE(0, 0);
    for (int ch = 0; ch < NC; ch += 2) {
        __syncthreads();
        STAGE(ch + 1, 1);
        AISSUE(ch + 1, Ar1);
        COMPUTE(0, Ar0);
        __syncthreads();
        if (ch + 2 < NC) { STAGE(ch + 2, 0); AISSUE(ch + 2, Ar0); }
        COMPUTE(1, Ar1);
    }

    constexpr float INV = 1.f / 4096.f;
    float lsum = 0.f;
    #pragma unroll
    for (int tt = 0; tt < CT; tt++) {
        int cg = col0 + wc * 64 + tt * 32 + cl;
        float bb = bias[cg];
        #pragma unroll
        for (int m = 0; m < 16; m++) {
            int rl = wr * 32 + (m & 3) + 8 * (m >> 2) + 4 * g32;
            float v = fmaf(acc[tt][m], INV, bb);
            size_t o = (size_t)(row0 + rl) * NF + cg;
            float e = v - rec[o];             // rec holds xn here
            lsum = fmaf(e, e, lsum);
            rec[o] = v;
        }
    }
    #pragma unroll
    for (int mask = 1; mask < 64; mask <<= 1) lsum += __shfl_xor(lsum, mask, 64);
    if (lane == 0) red[w] = lsum;
    __syncthreads();
    if (tid == 0) {
        float t = 0.f;
        #pragma unroll
        for (int i = 0; i < 8; i++) t += red[i];
        atomicAdd(loss_acc, t * (1.0f / ((float)NB * (float)DIN)));
    }
}

// ---------------- VQ: fp16 hi/lo split MFMA scores + partial argmin (v4) -----
// score = 4096||E||^2 + (-32 r)·(256 E)  (-2 folded into R scale)
// v4: OPERAND SWAP — mfma(codes_frag, rows_frag): A/B fragment register
// formats are identical (lane&31 = M/N index, lane>>5 = k-group), so LDS
// addressing and Rsp loads are unchanged; the output now holds 16 CODES x
// 1 ROW per thread -> running argmin needs only (best,bidx) = 2 regs/set and
// one shfl_xor(32) merge. Freed regs buy 64 rows/wave (2 row-sets): each
// code read feeds 6 MFMAs (LDS:MFMA = 1:3, was 2:3). 4-wave blocks, 32KB
// LDS, ~230 VGPR -> 2 blocks/CU resident; cross-block phase diversity
// overlaps the LDS-read phase with the MFMA phase (lockstep disease fix).
// grid (NB/256, 16 strips of 512 codes); products {EhRh,ElRh,EhRl} identical
// to the verified set (commutative); code scan order ascending -> strict <
// keeps first occurrence (numpy tie rule).
__global__ __launch_bounds__(256, 2) void k_vq_argmin_mfma(
    const _Float16* __restrict__ Rsp, const _Float16* __restrict__ Esp,
    const float* __restrict__ cbnS,
    float* __restrict__ pbest, int* __restrict__ pidx) {
    __shared__ __align__(16) _Float16 Es[2][8192];    // 2 x 16KB
    const int tid = threadIdx.x;
    const int w = tid >> 6, lane = tid & 63;
    const int g = lane >> 5, cl31 = lane & 31;
    const int rt0 = blockIdx.x * 256 + w * 64;        // wave's 64 rows
    const int cbase = blockIdx.y * 512;
    const int ch0 = blockIdx.y * 16;

    // B-operand row fragments (2 sets of 32 rows), persistent:
    // col = lane&31 -> row rt+cl31, k = kc*16 + g*8 + j (verified map)
    f16x8 Rh0[8], Rl0[8], Rh1[8], Rl1[8];
    {
        const _Float16* rp0 = Rsp + (size_t)(rt0 + cl31) * 256 + g * 8;
        const _Float16* rp1 = rp0 + 32 * 256;
        #pragma unroll
        for (int kc = 0; kc < 8; kc++) {
            Rh0[kc] = *(const f16x8*)(rp0 + kc * 16);
            Rl0[kc] = *(const f16x8*)(rp0 + 128 + kc * 16);
            Rh1[kc] = *(const f16x8*)(rp1 + kc * 16);
            Rl1[kc] = *(const f16x8*)(rp1 + 128 + kc * 16);
        }
    }

    float best0 = 3.402823466e+38f, best1 = 3.402823466e+38f;
    int bidx0 = 0, bidx1 = 0;

    auto STAGE = [&](int gch, int b) {
        const _Float16* gp = Esp + (size_t)gch * 8192;
        #pragma unroll
        for (int p = 0; p < 4; p++) {
            int f = tid + 256 * p;
            __builtin_amdgcn_global_load_lds(
                (const __attribute__((address_space(1))) void*)(gp + (size_t)f * 8),
                (__attribute__((address_space(3))) void*)(&Es[b][(size_t)f * 8]),
                16, 0, 0);
        }
    };

    STAGE(ch0, 0);
    for (int ch = 0; ch < 16; ch++) {
        const int buf = ch & 1;
        const int c0 = cbase + ch * 32;
        // cbn for the 16 codes this lane-half owns: m=4q+r -> code c0+4g+8q+r
        float cnv[16];
        #pragma unroll
        for (int q = 0; q < 4; q++) {
            float4 v = *(const float4*)(cbnS + c0 + q * 8 + 4 * g);
            cnv[q * 4 + 0] = v.x; cnv[q * 4 + 1] = v.y;
            cnv[q * 4 + 2] = v.z; cnv[q * 4 + 3] = v.w;
        }
        __syncthreads();                      // stage(ch) landed; buf readable
        if (ch < 15) STAGE(ch0 + ch + 1, buf ^ 1);
        f32x16 a00, a10, a01, a11;
        #pragma unroll
        for (int m = 0; m < 16; m++) { a00[m] = 0.f; a10[m] = 0.f; a01[m] = 0.f; a11[m] = 0.f; }
        __builtin_amdgcn_s_setprio(1);
        #pragma unroll
        for (int kc = 0; kc < 8; kc++) {
            int sh = kc * 2 + g;
            // A-operand (codes): M-row = cl31, contiguous 16B -> conflict-free
            f16x8 eh = *(const f16x8*)&Es[buf][sh * 256 + cl31 * 8];
            f16x8 el = *(const f16x8*)&Es[buf][(16 + sh) * 256 + cl31 * 8];
            a00 = __builtin_amdgcn_mfma_f32_32x32x16_f16(eh, Rh0[kc], a00, 0, 0, 0);
            a01 = __builtin_amdgcn_mfma_f32_32x32x16_f16(eh, Rh1[kc], a01, 0, 0, 0);
            a00 = __builtin_amdgcn_mfma_f32_32x32x16_f16(el, Rh0[kc], a00, 0, 0, 0);
            a01 = __builtin_amdgcn_mfma_f32_32x32x16_f16(el, Rh1[kc], a01, 0, 0, 0);
            a10 = __builtin_amdgcn_mfma_f32_32x32x16_f16(eh, Rl0[kc], a10, 0, 0, 0);
            a11 = __builtin_amdgcn_mfma_f32_32x32x16_f16(eh, Rl1[kc], a11, 0, 0, 0);
        }
        __builtin_amdgcn_s_setprio(0);
        // running argmin over the 16 codes (D-row m -> code (m&3)+8*(m>>2)+4g)
        const int c0g = c0 + 4 * g;
        #pragma unroll
        for (int m = 0; m < 16; m++) {
            int c = c0g + ((m & 3) + 8 * (m >> 2));
            float s0 = (a00[m] + a10[m]) + cnv[m];
            float s1 = (a01[m] + a11[m]) + cnv[m];
            if (s0 < best0) { best0 = s0; bidx0 = c; }
            if (s1 < best1) { best1 = s1; bidx1 = c; }
        }
    }

    // merge lane-halves (same row, complementary code sets); tie -> smaller idx
    {
        float ob = __shfl_xor(best0, 32, 64);
        int oi = __shfl_xor(bidx0, 32, 64);
        if (ob < best0 || (ob == best0 && oi < bidx0)) { best0 = ob; bidx0 = oi; }
        ob = __shfl_xor(best1, 32, 64);
        oi = __shfl_xor(bidx1, 32, 64);
        if (ob < best1 || (ob == best1 && oi < bidx1)) { best1 = ob; bidx1 = oi; }
    }
    if (lane < 32) {
        const int part = blockIdx.y;
        pbest[(size_t)part * NB + rt0 + cl31] = best0;
        pidx [(size_t)part * NB + rt0 + cl31] = bidx0;
        pbest[(size_t)part * NB + rt0 + 32 + cl31] = best1;
        pidx [(size_t)part * NB + rt0 + 32 + cl31] = bidx1;
    }
}

// merge the 16 strip-partials; tie -> smaller index
__global__ void k_vq_reduce(const float* __restrict__ pbest, const int* __restrict__ pidx,
                            int* __restrict__ idx_out, float* __restrict__ ids_f) {
    int row = blockIdx.x * 256 + threadIdx.x;
    float b = pbest[row];
    int bi = pidx[row];
    #pragma unroll
    for (int s = 1; s < 16; s++) {
        float ob = pbest[(size_t)s * NB + row];
        int oi = pidx[(size_t)s * NB + row];
        if (ob < b || (ob == b && oi < bi)) { b = ob; bi = oi; }
    }
    idx_out[row] = bi;
    ids_f[(size_t)row * 4] = (float)bi;
}

// gather + residual update + qsum + vq_loss partial; writes fp16 split (x -32)
__global__ void k_vq_update(const float* __restrict__ Rin, const int* __restrict__ idx,
                            const float* __restrict__ E, float* __restrict__ Rout,
                            float* __restrict__ qsum, float* __restrict__ vq_acc,
                            int firstq, _Float16* __restrict__ Rsp) {
    __shared__ float ps[4];
    int i = blockIdx.x * 256 + threadIdx.x;   // NB*128 total
    int row = i >> 7, d = i & 127;
    float e = E[(size_t)idx[row] * 128 + d];
    float rv = Rin[i] - e;
    Rout[i] = rv;
    qsum[i] = firstq ? e : (qsum[i] + e);
    float rs = rv * -32.f;
    _Float16 hi = (_Float16)rs;
    Rsp[(size_t)row * 256 + d] = hi;
    Rsp[(size_t)row * 256 + 128 + d] = (_Float16)(rs - (float)hi);
    float p = rv * rv;
    #pragma unroll
    for (int m = 1; m < 64; m <<= 1) p += __shfl_xor(p, m, 64);
    int lane = threadIdx.x & 63, wv = threadIdx.x >> 6;
    if (lane == 0) ps[wv] = p;
    __syncthreads();
    if (threadIdx.x == 0)
        atomicAdd(vq_acc, (ps[0] + ps[1] + ps[2] + ps[3]) * (1.25f / ((float)NB * 128.f)));
}

// ---------------- launch ----------------

extern "C" void kernel_launch(void* const* d_in, const int* in_sizes, int n_in,
                              void* d_out, int out_size, void* d_ws, size_t ws_size,
                              hipStream_t stream) {
    (void)in_sizes; (void)n_in; (void)out_size; (void)ws_size;
    const float* x        = (const float*)d_in[0];
    const float* emb_mean = (const float*)d_in[1];
    const float* emb_std  = (const float*)d_in[2];
    const float* enc_w0 = (const float*)d_in[3];
    const float* enc_b0 = (const float*)d_in[4];
    const float* enc_g0 = (const float*)d_in[5];
    const float* enc_w1 = (const float*)d_in[6];
    const float* enc_b1 = (const float*)d_in[7];
    const float* enc_g1 = (const float*)d_in[8];
    const float* enc_w2 = (const float*)d_in[9];
    const float* enc_b2 = (const float*)d_in[10];
    const float* enc_g2 = (const float*)d_in[11];
    const float* cb     = (const float*)d_in[12];
    const float* dec_w0 = (const float*)d_in[13];
    const float* dec_b0 = (const float*)d_in[14];
    const float* dec_g0 = (const float*)d_in[15];
    const float* dec_w1 = (const float*)d_in[16];
    const float* dec_b1 = (const float*)d_in[17];
    const float* dec_g1 = (const float*)d_in[18];
    const float* dec_w2 = (const float*)d_in[19];
    const float* dec_b2 = (const float*)d_in[20];

    float* out   = (float*)d_out;
    float* xn    = out;                        // recon region doubles as xn scratch
    float* ids_f = out + (size_t)NB * DIN;
    float* rl    = out + (size_t)NB * DIN + (size_t)NB * 4;
    float* vl    = rl + 1;

    float* ws   = (float*)d_ws;
    float* h0   = ws;                           // 16384*512
    float* h1   = h0 + (size_t)NB * 512;        // 16384*256
    float* h2   = h1 + (size_t)NB * 256;        // 16384*128
    float* rbuf = h2 + (size_t)NB * 128;        // 16384*128
    float* qsum = rbuf + (size_t)NB * 128;      // 16384*128
    float* cbn  = qsum + (size_t)NB * 128;      // 4*8192
    int*   idxb = (int*)(cbn + 4 * 8192);       // 16384

    // VQ scratch in h0 (free between enc1-read and dec1-write):
    //   pbest 16*NB f, pidx 16*NB i, Rsp NB*256 halfs, Esp 4*8192*256 halfs
    //   = 0.52M + 2.10M + 4.19M float-equiv = 6.82M < 8.39M.
    float*    pbest = h0;                                   // 16*16384
    int*      pidx  = (int*)(h0 + 16 * (size_t)NB);         // 16*16384
    _Float16* Rsp   = (_Float16*)(h0 + 32 * (size_t)NB);
    _Float16* Esp   = (_Float16*)(h0 + 32 * (size_t)NB + (size_t)NB * 128);

    // weight splits live in rbuf: enc set dead before VQ writes rbuf (q=0
    // update); dec set written after the last vq_update reads rbuf.
    _Float16* WtE0 = (_Float16*)rbuf;           // 768*512*2 = 786432 halfs
    _Float16* WtE1 = WtE0 + 786432;             // 512*256*2 = 262144
    _Float16* WtE2 = WtE0 + 1048576;            // 256*128*2 =  65536
    _Float16* WtD0 = (_Float16*)rbuf;           // 128*256*2 =  65536
    _Float16* WtD1 = WtD0 + 65536;              // 256*512*2 = 262144
    _Float16* WtD2 = WtD0 + 327680;             // 512*768*2 = 786432

    k_zero2<<<1, 64, 0, stream>>>(rl, vl);
    k_norm<<<(NB * DIN) / 256, 256, 0, stream>>>(x, emb_mean, emb_std, xn);
    k_cbnorm<<<(4 * 8192) / 4, 256, 0, stream>>>(cb, cbn);

    k_wsplit<<<(768 * 512) / 256, 256, 0, stream>>>(enc_w0, WtE0, 768, 512);
    k_wsplit<<<(512 * 256) / 256, 256, 0, stream>>>(enc_w1, WtE1, 512, 256);
    k_wsplit<<<(256 * 128) / 256, 256, 0, stream>>>(enc_w2, WtE2, 256, 128);

    k_mfma_rms<512><<<NB / 64, 512, 0, stream>>>(xn, WtE0, enc_b0, enc_g0, h0, 768);
    k_mfma_rms<256><<<NB / 64, 512, 0, stream>>>(h0, WtE1, enc_b1, enc_g1, h1, 512);
    k_mfma_rms<128><<<NB / 64, 512, 0, stream>>>(h1, WtE2, enc_b2, enc_g2, h2, 256);

    // fp16 splits for VQ (into h0 region, after enc1 consumed h0)
    k_esplit<<<(4 * 8192 * 128) / 256, 256, 0, stream>>>(cb, Esp);
    k_split<<<(NB * 128) / 256, 256, 0, stream>>>(h2, Rsp, -32.f);

    for (int q = 0; q < 4; q++) {
        const float* R = (q == 0) ? h2 : rbuf;
        const float* Eq = cb + (size_t)q * 8192 * 128;
        const _Float16* EspQ = Esp + (size_t)q * 2097152;
        dim3 gq(NB / 256, 16);
        k_vq_argmin_mfma<<<gq, 256, 0, stream>>>(Rsp, EspQ, cbn + q * 8192, pbest, pidx);
        k_vq_reduce<<<NB / 256, 256, 0, stream>>>(pbest, pidx, idxb, ids_f + q);
        k_vq_update<<<(NB * 128) / 256, 256, 0, stream>>>(R, idxb, Eq, rbuf, qsum, vl,
                                                          q == 0 ? 1 : 0, Rsp);
    }

    // dec weight splits (rbuf dead after last vq_update)
    k_wsplit<<<(128 * 256) / 256, 256, 0, stream>>>(dec_w0, WtD0, 128, 256);
    k_wsplit<<<(256 * 512) / 256, 256, 0, stream>>>(dec_w1, WtD1, 256, 512);
    k_wsplit<<<(512 * 768) / 256, 256, 0, stream>>>(dec_w2, WtD2, 512, 768);

    k_mfma_rms<256><<<NB / 64, 512, 0, stream>>>(qsum, WtD0, dec_b0, dec_g0, h1, 128);
    k_mfma_rms<512><<<NB / 64, 512, 0, stream>>>(h1, WtD1, dec_b1, dec_g1, h0, 256);

    dim3 g2(NB / 64, 3);
    k_mfma_dec2<<<g2, 512, 0, stream>>>(h0, WtD2, dec_b2, xn, rl, 512);
}

// Round 6
// 865.659 us; speedup vs baseline: 3.7609x; 1.4492x over previous
//
#include <hip/hip_runtime.h>
#include <math.h>

#define NB 16384
#define DIN 768

typedef _Float16 f16x8 __attribute__((ext_vector_type(8)));
typedef float f32x16 __attribute__((ext_vector_type(16)));

// ---------------- small kernels ----------------

__global__ void k_zero2(float* a, float* b) {
    if (threadIdx.x == 0) { *a = 0.f; *b = 0.f; }
}

__global__ void k_norm(const float* __restrict__ x, const float* __restrict__ m,
                       const float* __restrict__ s, float* __restrict__ xn) {
    int i = blockIdx.x * 256 + threadIdx.x;          // 16384*768 total
    int j = i % DIN;
    xn[i] = (x[i] - m[j]) / s[j];
}

// one 64-lane wave per codebook row; writes ||E||^2 * 4096 (r*-32, E*256 scaling)
__global__ void k_cbnorm(const float* __restrict__ cb, float* __restrict__ cbn) {
    int row = blockIdx.x * 4 + (threadIdx.x >> 6);
    int lane = threadIdx.x & 63;
    const float* p = cb + (size_t)row * 128;
    float v0 = p[lane], v1 = p[lane + 64];
    float s = v0 * v0 + v1 * v1;
    #pragma unroll
    for (int m = 32; m >= 1; m >>= 1) s += __shfl_xor(s, m, 64);
    if (lane == 0) cbn[row] = s * 4096.f;
}

// split fp32 rows (n x 128) into fp16 hi|lo layout (n x 256): [hi(128) | lo(128)]
__global__ void k_split(const float* __restrict__ src, _Float16* __restrict__ dst,
                        float scale) {
    int i = blockIdx.x * 256 + threadIdx.x;   // n*128 elements
    int row = i >> 7, d = i & 127;
    float v = src[i] * scale;
    _Float16 hi = (_Float16)v;
    dst[(size_t)row * 256 + d] = hi;
    dst[(size_t)row * 256 + 128 + d] = (_Float16)(v - (float)hi);
}

// E split into per-chunk granule layout (32-code chunks) consumed linearly
// by global_load_lds: chunk ch = c>>5; halfs offset =
//   q*2097152 + ch*8192 + slice*256 + (c&31)*8 + (k&7)
// slice = k>>3 (hi) / 16 + (k>>3) (lo). Scale 256.
__global__ void k_esplit(const float* __restrict__ cb, _Float16* __restrict__ Esp) {
    int i = blockIdx.x * 256 + threadIdx.x;   // 4*8192*128 total
    int q = i >> 20;
    int rem = i & 1048575;
    int c = rem >> 7, k = rem & 127;
    float v = cb[i] * 256.f;
    _Float16 hi = (_Float16)v;
    _Float16 lo = (_Float16)(v - (float)hi);
    int sh = k >> 3, j = k & 7;
    size_t base = (size_t)q * 2097152 + (size_t)(c >> 5) * 8192 + (size_t)(c & 31) * 8 + j;
    Esp[base + (size_t)sh * 256] = hi;
    Esp[base + (size_t)(16 + sh) * 256] = lo;
}

// ---------------- weight transpose-split into chunked granule layout ----------
// W (K x N fp32) -> Wt halfs, granule (kc, s, c): ((kc*8+s)*N + c)*8 + j
// k = kc*32 + t*16 + g*8 + j ; s = t*2+g (hi), 4+t*2+g (lo). Scale 256.
__global__ void k_wsplit(const float* __restrict__ W, _Float16* __restrict__ Wt,
                         int K, int N) {
    int i = blockIdx.x * 256 + threadIdx.x;   // K*N total
    int k = i / N, c = i - k * N;
    float v = W[i] * 256.f;
    _Float16 hi = (_Float16)v;
    _Float16 lo = (_Float16)(v - (float)hi);
    int kc = k >> 5, kin = k & 31;
    int t = kin >> 4, gg = (kin >> 3) & 1, j = kin & 7;
    size_t base = ((size_t)(kc * 8) * N + c) * 8 + j;
    Wt[base + (size_t)(t * 2 + gg) * N * 8] = hi;
    Wt[base + (size_t)(4 + t * 2 + gg) * N * 8] = lo;
}

// ---------------- fused MFMA Linear + ReLU + RMSNorm ----------------
// (unchanged, verified round 2)
template <int N>
__global__ __launch_bounds__(512, 2) void k_mfma_rms(
    const float* __restrict__ A, const _Float16* __restrict__ Wt,
    const float* __restrict__ bias, const float* __restrict__ g,
    float* __restrict__ out, int K) {
    constexpr int CT = N / 128;               // col-tiles per wave
    __shared__ __align__(16) _Float16 Bs[2][N * 64];
    __shared__ float ssbuf[64][4];
    const int tid = threadIdx.x;
    const int w = tid >> 6, lane = tid & 63;
    const int wr = w >> 2, wc = w & 3;
    const int g32 = lane >> 5, cl = lane & 31;
    const int row0 = blockIdx.x * 64;
    const int NC = K >> 5;                    // chunks of 32 k (always even)

    const float* ap = A + (size_t)(row0 + wr * 32 + cl) * K + g32 * 8;

    f32x16 acc[CT];
    #pragma unroll
    for (int tt = 0; tt < CT; tt++)
        #pragma unroll
        for (int m = 0; m < 16; m++) acc[tt][m] = 0.f;

    float4 Ar0[4], Ar1[4];

    auto STAGE = [&](int ch, int b) {
        const _Float16* gp = Wt + (size_t)ch * 8 * N * 8;
        #pragma unroll
        for (int p = 0; p < N / 64; p++) {
            int f = tid + 512 * p;
            __builtin_amdgcn_global_load_lds(
                (const __attribute__((address_space(1))) void*)(gp + (size_t)f * 8),
                (__attribute__((address_space(3))) void*)(&Bs[b][(size_t)f * 8]),
                16, 0, 0);
        }
    };
    auto AISSUE = [&](int ch, float4* Ar) {
        const float* bsrc = ap + ch * 32;
        Ar[0] = *(const float4*)(bsrc);
        Ar[1] = *(const float4*)(bsrc + 4);
        Ar[2] = *(const float4*)(bsrc + 16);
        Ar[3] = *(const float4*)(bsrc + 20);
    };
    auto COMPUTE = [&](int b, const float4* Ar) {
        #pragma unroll
        for (int t = 0; t < 2; t++) {
            float vv[8] = {Ar[t * 2].x, Ar[t * 2].y, Ar[t * 2].z, Ar[t * 2].w,
                           Ar[t * 2 + 1].x, Ar[t * 2 + 1].y, Ar[t * 2 + 1].z, Ar[t * 2 + 1].w};
            f16x8 ah, al;
            #pragma unroll
            for (int j = 0; j < 8; j++) {
                float v = vv[j] * 16.f;
                _Float16 h = (_Float16)v;
                ah[j] = h;
                al[j] = (_Float16)(v - (float)h);
            }
            #pragma unroll
            for (int tt = 0; tt < CT; tt++) {
                int c = wc * (N / 4) + tt * 32 + cl;
                f16x8 bh = *(const f16x8*)&Bs[b][((size_t)(t * 2 + g32) * N + c) * 8];
                f16x8 bl = *(const f16x8*)&Bs[b][((size_t)(4 + t * 2 + g32) * N + c) * 8];
                acc[tt] = __builtin_amdgcn_mfma_f32_32x32x16_f16(ah, bh, acc[tt], 0, 0, 0);
                acc[tt] = __builtin_amdgcn_mfma_f32_32x32x16_f16(al, bh, acc[tt], 0, 0, 0);
                acc[tt] = __builtin_amdgcn_mfma_f32_32x32x16_f16(ah, bl, acc[tt], 0, 0, 0);
            }
        }
    };

    AISSUE(0, Ar0);
    STAGE(0, 0);
    for (int ch = 0; ch < NC; ch += 2) {
        __syncthreads();                      // drains stage(ch) + A loads
        STAGE(ch + 1, 1);
        AISSUE(ch + 1, Ar1);
        COMPUTE(0, Ar0);
        __syncthreads();                      // drains stage(ch+1)
        if (ch + 2 < NC) { STAGE(ch + 2, 0); AISSUE(ch + 2, Ar0); }
        COMPUTE(1, Ar1);
    }

    // epilogue: /4096 + bias + relu + rmsnorm
    constexpr float INV = 1.f / 4096.f;
    float bb[CT], gv[CT];
    #pragma unroll
    for (int tt = 0; tt < CT; tt++) {
        int c = wc * (N / 4) + tt * 32 + cl;
        bb[tt] = bias[c];
        gv[tt] = g[c];
    }
    float ssm[16];
    #pragma unroll
    for (int m = 0; m < 16; m++) ssm[m] = 0.f;
    #pragma unroll
    for (int tt = 0; tt < CT; tt++)
        #pragma unroll
        for (int m = 0; m < 16; m++) {
            float v = fmaf(acc[tt][m], INV, bb[tt]);
            v = v > 0.f ? v : 0.f;
            acc[tt][m] = v;
            ssm[m] = fmaf(v, v, ssm[m]);
        }
    #pragma unroll
    for (int mask = 1; mask < 32; mask <<= 1)
        #pragma unroll
        for (int m = 0; m < 16; m++) ssm[m] += __shfl_xor(ssm[m], mask, 64);
    if (cl == 0) {
        #pragma unroll
        for (int m = 0; m < 16; m++) {
            int rl = wr * 32 + (m & 3) + 8 * (m >> 2) + 4 * g32;
            ssbuf[rl][wc] = ssm[m];
        }
    }
    __syncthreads();
    #pragma unroll
    for (int m = 0; m < 16; m++) {
        int rl = wr * 32 + (m & 3) + 8 * (m >> 2) + 4 * g32;
        float s4 = (ssbuf[rl][0] + ssbuf[rl][1]) + (ssbuf[rl][2] + ssbuf[rl][3]);
        float sc = 1.0f / sqrtf(s4 * (1.0f / (float)N) + 1e-6f);
        #pragma unroll
        for (int tt = 0; tt < CT; tt++) {
            int c = wc * (N / 4) + tt * 32 + cl;
            out[(size_t)(row0 + rl) * N + c] = acc[tt][m] * sc * gv[tt];
        }
    }
}

// ---------------- final MFMA Linear (512->768) + recon loss ----------------
// (unchanged, verified round 2)
__global__ __launch_bounds__(512, 2) void k_mfma_dec2(
    const float* __restrict__ A, const _Float16* __restrict__ Wt,
    const float* __restrict__ bias, float* __restrict__ rec,
    float* __restrict__ loss_acc, int K) {
    constexpr int NT = 256, NF = 768, CT = 2;
    __shared__ __align__(16) _Float16 Bs[2][NT * 64];
    __shared__ float red[8];
    const int tid = threadIdx.x;
    const int w = tid >> 6, lane = tid & 63;
    const int wr = w >> 2, wc = w & 3;
    const int g32 = lane >> 5, cl = lane & 31;
    const int row0 = blockIdx.x * 64;
    const int col0 = blockIdx.y * NT;
    const int NC = K >> 5;

    const float* ap = A + (size_t)(row0 + wr * 32 + cl) * K + g32 * 8;

    f32x16 acc[CT];
    #pragma unroll
    for (int tt = 0; tt < CT; tt++)
        #pragma unroll
        for (int m = 0; m < 16; m++) acc[tt][m] = 0.f;

    float4 Ar0[4], Ar1[4];

    auto STAGE = [&](int ch, int b) {
        #pragma unroll
        for (int p = 0; p < 4; p++) {
            int f = tid + 512 * p;
            int s = f >> 8, cloc = f & 255;
            const _Float16* gp = Wt + ((size_t)(ch * 8 + s) * NF + col0 + cloc) * 8;
            __builtin_amdgcn_global_load_lds(
                (const __attribute__((address_space(1))) void*)gp,
                (__attribute__((address_space(3))) void*)(&Bs[b][(size_t)f * 8]),
                16, 0, 0);
        }
    };
    auto AISSUE = [&](int ch, float4* Ar) {
        const float* bsrc = ap + ch * 32;
        Ar[0] = *(const float4*)(bsrc);
        Ar[1] = *(const float4*)(bsrc + 4);
        Ar[2] = *(const float4*)(bsrc + 16);
        Ar[3] = *(const float4*)(bsrc + 20);
    };
    auto COMPUTE = [&](int b, const float4* Ar) {
        #pragma unroll
        for (int t = 0; t < 2; t++) {
            float vv[8] = {Ar[t * 2].x, Ar[t * 2].y, Ar[t * 2].z, Ar[t * 2].w,
                           Ar[t * 2 + 1].x, Ar[t * 2 + 1].y, Ar[t * 2 + 1].z, Ar[t * 2 + 1].w};
            f16x8 ah, al;
            #pragma unroll
            for (int j = 0; j < 8; j++) {
                float v = vv[j] * 16.f;
                _Float16 h = (_Float16)v;
                ah[j] = h;
                al[j] = (_Float16)(v - (float)h);
            }
            #pragma unroll
            for (int tt = 0; tt < CT; tt++) {
                int c = wc * 64 + tt * 32 + cl;
                f16x8 bh = *(const f16x8*)&Bs[b][((size_t)(t * 2 + g32) * NT + c) * 8];
                f16x8 bl = *(const f16x8*)&Bs[b][((size_t)(4 + t * 2 + g32) * NT + c) * 8];
                acc[tt] = __builtin_amdgcn_mfma_f32_32x32x16_f16(ah, bh, acc[tt], 0, 0, 0);
                acc[tt] = __builtin_amdgcn_mfma_f32_32x32x16_f16(al, bh, acc[tt], 0, 0, 0);
                acc[tt] = __builtin_amdgcn_mfma_f32_32x32x16_f16(ah, bl, acc[tt], 0, 0, 0);
            }
        }
    };

    AISSUE(0, Ar0);
    STAGE(0, 0);
    for (int ch = 0; ch < NC; ch += 2) {
        __syncthreads();
        STAGE(ch + 1, 1);
        AISSUE(ch + 1, Ar1);
        COMPUTE(0, Ar0);
        __syncthreads();
        if (ch + 2 < NC) { STAGE(ch + 2, 0); AISSUE(ch + 2, Ar0); }
        COMPUTE(1, Ar1);
    }

    constexpr float INV = 1.f / 4096.f;
    float lsum = 0.f;
    #pragma unroll
    for (int tt = 0; tt < CT; tt++) {
        int cg = col0 + wc * 64 + tt * 32 + cl;
        float bb = bias[cg];
        #pragma unroll
        for (int m = 0; m < 16; m++) {
            int rl = wr * 32 + (m & 3) + 8 * (m >> 2) + 4 * g32;
            float v = fmaf(acc[tt][m], INV, bb);
            size_t o = (size_t)(row0 + rl) * NF + cg;
            float e = v - rec[o];             // rec holds xn here
            lsum = fmaf(e, e, lsum);
            rec[o] = v;
        }
    }
    #pragma unroll
    for (int mask = 1; mask < 64; mask <<= 1) lsum += __shfl_xor(lsum, mask, 64);
    if (lane == 0) red[w] = lsum;
    __syncthreads();
    if (tid == 0) {
        float t = 0.f;
        #pragma unroll
        for (int i = 0; i < 8; i++) t += red[i];
        atomicAdd(loss_acc, t * (1.0f / ((float)NB * (float)DIN)));
    }
}

// ---------------- VQ: fp16 hi/lo split MFMA scores + partial argmin (v4) -----
// (unchanged, verified round 5)
__global__ __launch_bounds__(256, 2) void k_vq_argmin_mfma(
    const _Float16* __restrict__ Rsp, const _Float16* __restrict__ Esp,
    const float* __restrict__ cbnS,
    float* __restrict__ pbest, int* __restrict__ pidx) {
    __shared__ __align__(16) _Float16 Es[2][8192];    // 2 x 16KB
    const int tid = threadIdx.x;
    const int w = tid >> 6, lane = tid & 63;
    const int g = lane >> 5, cl31 = lane & 31;
    const int rt0 = blockIdx.x * 256 + w * 64;        // wave's 64 rows
    const int cbase = blockIdx.y * 512;
    const int ch0 = blockIdx.y * 16;

    f16x8 Rh0[8], Rl0[8], Rh1[8], Rl1[8];
    {
        const _Float16* rp0 = Rsp + (size_t)(rt0 + cl31) * 256 + g * 8;
        const _Float16* rp1 = rp0 + 32 * 256;
        #pragma unroll
        for (int kc = 0; kc < 8; kc++) {
            Rh0[kc] = *(const f16x8*)(rp0 + kc * 16);
            Rl0[kc] = *(const f16x8*)(rp0 + 128 + kc * 16);
            Rh1[kc] = *(const f16x8*)(rp1 + kc * 16);
            Rl1[kc] = *(const f16x8*)(rp1 + 128 + kc * 16);
        }
    }

    float best0 = 3.402823466e+38f, best1 = 3.402823466e+38f;
    int bidx0 = 0, bidx1 = 0;

    auto STAGE = [&](int gch, int b) {
        const _Float16* gp = Esp + (size_t)gch * 8192;
        #pragma unroll
        for (int p = 0; p < 4; p++) {
            int f = tid + 256 * p;
            __builtin_amdgcn_global_load_lds(
                (const __attribute__((address_space(1))) void*)(gp + (size_t)f * 8),
                (__attribute__((address_space(3))) void*)(&Es[b][(size_t)f * 8]),
                16, 0, 0);
        }
    };

    STAGE(ch0, 0);
    for (int ch = 0; ch < 16; ch++) {
        const int buf = ch & 1;
        const int c0 = cbase + ch * 32;
        float cnv[16];
        #pragma unroll
        for (int q = 0; q < 4; q++) {
            float4 v = *(const float4*)(cbnS + c0 + q * 8 + 4 * g);
            cnv[q * 4 + 0] = v.x; cnv[q * 4 + 1] = v.y;
            cnv[q * 4 + 2] = v.z; cnv[q * 4 + 3] = v.w;
        }
        __syncthreads();                      // stage(ch) landed; buf readable
        if (ch < 15) STAGE(ch0 + ch + 1, buf ^ 1);
        f32x16 a00, a10, a01, a11;
        #pragma unroll
        for (int m = 0; m < 16; m++) { a00[m] = 0.f; a10[m] = 0.f; a01[m] = 0.f; a11[m] = 0.f; }
        __builtin_amdgcn_s_setprio(1);
        #pragma unroll
        for (int kc = 0; kc < 8; kc++) {
            int sh = kc * 2 + g;
            f16x8 eh = *(const f16x8*)&Es[buf][sh * 256 + cl31 * 8];
            f16x8 el = *(const f16x8*)&Es[buf][(16 + sh) * 256 + cl31 * 8];
            a00 = __builtin_amdgcn_mfma_f32_32x32x16_f16(eh, Rh0[kc], a00, 0, 0, 0);
            a01 = __builtin_amdgcn_mfma_f32_32x32x16_f16(eh, Rh1[kc], a01, 0, 0, 0);
            a00 = __builtin_amdgcn_mfma_f32_32x32x16_f16(el, Rh0[kc], a00, 0, 0, 0);
            a01 = __builtin_amdgcn_mfma_f32_32x32x16_f16(el, Rh1[kc], a01, 0, 0, 0);
            a10 = __builtin_amdgcn_mfma_f32_32x32x16_f16(eh, Rl0[kc], a10, 0, 0, 0);
            a11 = __builtin_amdgcn_mfma_f32_32x32x16_f16(eh, Rl1[kc], a11, 0, 0, 0);
        }
        __builtin_amdgcn_s_setprio(0);
        const int c0g = c0 + 4 * g;
        #pragma unroll
        for (int m = 0; m < 16; m++) {
            int c = c0g + ((m & 3) + 8 * (m >> 2));
            float s0 = (a00[m] + a10[m]) + cnv[m];
            float s1 = (a01[m] + a11[m]) + cnv[m];
            if (s0 < best0) { best0 = s0; bidx0 = c; }
            if (s1 < best1) { best1 = s1; bidx1 = c; }
        }
    }

    {
        float ob = __shfl_xor(best0, 32, 64);
        int oi = __shfl_xor(bidx0, 32, 64);
        if (ob < best0 || (ob == best0 && oi < bidx0)) { best0 = ob; bidx0 = oi; }
        ob = __shfl_xor(best1, 32, 64);
        oi = __shfl_xor(bidx1, 32, 64);
        if (ob < best1 || (ob == best1 && oi < bidx1)) { best1 = ob; bidx1 = oi; }
    }
    if (lane < 32) {
        const int part = blockIdx.y;
        pbest[(size_t)part * NB + rt0 + cl31] = best0;
        pidx [(size_t)part * NB + rt0 + cl31] = bidx0;
        pbest[(size_t)part * NB + rt0 + 32 + cl31] = best1;
        pidx [(size_t)part * NB + rt0 + 32 + cl31] = bidx1;
    }
}

// merge the 16 strip-partials; tie -> smaller index
__global__ void k_vq_reduce(const float* __restrict__ pbest, const int* __restrict__ pidx,
                            int* __restrict__ idx_out, float* __restrict__ ids_f) {
    int row = blockIdx.x * 256 + threadIdx.x;
    float b = pbest[row];
    int bi = pidx[row];
    #pragma unroll
    for (int s = 1; s < 16; s++) {
        float ob = pbest[(size_t)s * NB + row];
        int oi = pidx[(size_t)s * NB + row];
        if (ob < b || (ob == b && oi < bi)) { b = ob; bi = oi; }
    }
    idx_out[row] = bi;
    ids_f[(size_t)row * 4] = (float)bi;
}

// gather + residual update + qsum + vq_loss partial (v2):
// 8 elem/thread, float4x2 + f16x8 vector traffic; NO atomics — per-block
// partial ||rv||^2 written to part[]; k_vq_acc sums all 4 x 1024 at the end.
__global__ void k_vq_update(const float* __restrict__ Rin, const int* __restrict__ idx,
                            const float* __restrict__ E, float* __restrict__ Rout,
                            float* __restrict__ qsum, float* __restrict__ part,
                            int firstq, _Float16* __restrict__ Rsp) {
    __shared__ float ps[4];
    int t = blockIdx.x * 256 + threadIdx.x;   // NB*128/8 threads
    int i0 = t * 8;
    int row = i0 >> 7, d0 = i0 & 127;
    const float* ep = E + (size_t)idx[row] * 128 + d0;
    float4 e0 = *(const float4*)ep, e1 = *(const float4*)(ep + 4);
    float4 r0 = *(const float4*)&Rin[i0], r1 = *(const float4*)&Rin[i0 + 4];
    float rv[8] = {r0.x - e0.x, r0.y - e0.y, r0.z - e0.z, r0.w - e0.w,
                   r1.x - e1.x, r1.y - e1.y, r1.z - e1.z, r1.w - e1.w};
    *(float4*)&Rout[i0]     = make_float4(rv[0], rv[1], rv[2], rv[3]);
    *(float4*)&Rout[i0 + 4] = make_float4(rv[4], rv[5], rv[6], rv[7]);
    if (firstq) {
        *(float4*)&qsum[i0] = e0;
        *(float4*)&qsum[i0 + 4] = e1;
    } else {
        float4 q0 = *(const float4*)&qsum[i0], q1 = *(const float4*)&qsum[i0 + 4];
        *(float4*)&qsum[i0]     = make_float4(q0.x + e0.x, q0.y + e0.y, q0.z + e0.z, q0.w + e0.w);
        *(float4*)&qsum[i0 + 4] = make_float4(q1.x + e1.x, q1.y + e1.y, q1.z + e1.z, q1.w + e1.w);
    }
    f16x8 hi, lo;
    float p = 0.f;
    #pragma unroll
    for (int j = 0; j < 8; j++) {
        float rs = rv[j] * -32.f;
        _Float16 h = (_Float16)rs;
        hi[j] = h;
        lo[j] = (_Float16)(rs - (float)h);
        p = fmaf(rv[j], rv[j], p);
    }
    *(f16x8*)&Rsp[(size_t)row * 256 + d0] = hi;
    *(f16x8*)&Rsp[(size_t)row * 256 + 128 + d0] = lo;
    #pragma unroll
    for (int m = 1; m < 64; m <<= 1) p += __shfl_xor(p, m, 64);
    int lane = threadIdx.x & 63, wv = threadIdx.x >> 6;
    if (lane == 0) ps[wv] = p;
    __syncthreads();
    if (threadIdx.x == 0)
        part[blockIdx.x] = (ps[0] + ps[1]) + (ps[2] + ps[3]);
}

// sum the 4*1024 per-block partials into the vq_loss scalar (single writer)
__global__ void k_vq_acc(const float* __restrict__ part, float* __restrict__ vl) {
    __shared__ float ps[4];
    float s = 0.f;
    for (int i = threadIdx.x; i < 4096; i += 256) s += part[i];
    #pragma unroll
    for (int m = 1; m < 64; m <<= 1) s += __shfl_xor(s, m, 64);
    int lane = threadIdx.x & 63, wv = threadIdx.x >> 6;
    if (lane == 0) ps[wv] = s;
    __syncthreads();
    if (threadIdx.x == 0)
        *vl = ((ps[0] + ps[1]) + (ps[2] + ps[3])) * (1.25f / ((float)NB * 128.f));
}

// ---------------- launch ----------------

extern "C" void kernel_launch(void* const* d_in, const int* in_sizes, int n_in,
                              void* d_out, int out_size, void* d_ws, size_t ws_size,
                              hipStream_t stream) {
    (void)in_sizes; (void)n_in; (void)out_size; (void)ws_size;
    const float* x        = (const float*)d_in[0];
    const float* emb_mean = (const float*)d_in[1];
    const float* emb_std  = (const float*)d_in[2];
    const float* enc_w0 = (const float*)d_in[3];
    const float* enc_b0 = (const float*)d_in[4];
    const float* enc_g0 = (const float*)d_in[5];
    const float* enc_w1 = (const float*)d_in[6];
    const float* enc_b1 = (const float*)d_in[7];
    const float* enc_g1 = (const float*)d_in[8];
    const float* enc_w2 = (const float*)d_in[9];
    const float* enc_b2 = (const float*)d_in[10];
    const float* enc_g2 = (const float*)d_in[11];
    const float* cb     = (const float*)d_in[12];
    const float* dec_w0 = (const float*)d_in[13];
    const float* dec_b0 = (const float*)d_in[14];
    const float* dec_g0 = (const float*)d_in[15];
    const float* dec_w1 = (const float*)d_in[16];
    const float* dec_b1 = (const float*)d_in[17];
    const float* dec_g1 = (const float*)d_in[18];
    const float* dec_w2 = (const float*)d_in[19];
    const float* dec_b2 = (const float*)d_in[20];

    float* out   = (float*)d_out;
    float* xn    = out;                        // recon region doubles as xn scratch
    float* ids_f = out + (size_t)NB * DIN;
    float* rl    = out + (size_t)NB * DIN + (size_t)NB * 4;
    float* vl    = rl + 1;

    float* ws   = (float*)d_ws;
    float* h0   = ws;                           // 16384*512
    float* h1   = h0 + (size_t)NB * 512;        // 16384*256
    float* h2   = h1 + (size_t)NB * 256;        // 16384*128
    float* rbuf = h2 + (size_t)NB * 128;        // 16384*128
    float* qsum = rbuf + (size_t)NB * 128;      // 16384*128
    float* cbn  = qsum + (size_t)NB * 128;      // 4*8192
    int*   idxb = (int*)(cbn + 4 * 8192);       // 16384
    float* vqp  = (float*)(idxb + NB);          // 4*1024 loss partials

    // VQ scratch in h0 (free between enc1-read and dec1-write):
    float*    pbest = h0;                                   // 16*16384
    int*      pidx  = (int*)(h0 + 16 * (size_t)NB);         // 16*16384
    _Float16* Rsp   = (_Float16*)(h0 + 32 * (size_t)NB);
    _Float16* Esp   = (_Float16*)(h0 + 32 * (size_t)NB + (size_t)NB * 128);

    // weight splits live in rbuf: enc set dead before VQ writes rbuf (q=0
    // update); dec set written after the last vq_update reads rbuf.
    _Float16* WtE0 = (_Float16*)rbuf;           // 768*512*2 = 786432 halfs
    _Float16* WtE1 = WtE0 + 786432;             // 512*256*2 = 262144
    _Float16* WtE2 = WtE0 + 1048576;            // 256*128*2 =  65536
    _Float16* WtD0 = (_Float16*)rbuf;           // 128*256*2 =  65536
    _Float16* WtD1 = WtD0 + 65536;              // 256*512*2 = 262144
    _Float16* WtD2 = WtD0 + 327680;             // 512*768*2 = 786432

    k_zero2<<<1, 64, 0, stream>>>(rl, vl);
    k_norm<<<(NB * DIN) / 256, 256, 0, stream>>>(x, emb_mean, emb_std, xn);
    k_cbnorm<<<(4 * 8192) / 4, 256, 0, stream>>>(cb, cbn);

    k_wsplit<<<(768 * 512) / 256, 256, 0, stream>>>(enc_w0, WtE0, 768, 512);
    k_wsplit<<<(512 * 256) / 256, 256, 0, stream>>>(enc_w1, WtE1, 512, 256);
    k_wsplit<<<(256 * 128) / 256, 256, 0, stream>>>(enc_w2, WtE2, 256, 128);

    k_mfma_rms<512><<<NB / 64, 512, 0, stream>>>(xn, WtE0, enc_b0, enc_g0, h0, 768);
    k_mfma_rms<256><<<NB / 64, 512, 0, stream>>>(h0, WtE1, enc_b1, enc_g1, h1, 512);
    k_mfma_rms<128><<<NB / 64, 512, 0, stream>>>(h1, WtE2, enc_b2, enc_g2, h2, 256);

    // fp16 splits for VQ (into h0 region, after enc1 consumed h0)
    k_esplit<<<(4 * 8192 * 128) / 256, 256, 0, stream>>>(cb, Esp);
    k_split<<<(NB * 128) / 256, 256, 0, stream>>>(h2, Rsp, -32.f);

    for (int q = 0; q < 4; q++) {
        const float* R = (q == 0) ? h2 : rbuf;
        const float* Eq = cb + (size_t)q * 8192 * 128;
        const _Float16* EspQ = Esp + (size_t)q * 2097152;
        dim3 gq(NB / 256, 16);
        k_vq_argmin_mfma<<<gq, 256, 0, stream>>>(Rsp, EspQ, cbn + q * 8192, pbest, pidx);
        k_vq_reduce<<<NB / 256, 256, 0, stream>>>(pbest, pidx, idxb, ids_f + q);
        k_vq_update<<<(NB * 128) / 2048, 256, 0, stream>>>(R, idxb, Eq, rbuf, qsum,
                                                           vqp + q * 1024, q == 0 ? 1 : 0, Rsp);
    }
    k_vq_acc<<<1, 256, 0, stream>>>(vqp, vl);

    // dec weight splits (rbuf dead after last vq_update)
    k_wsplit<<<(128 * 256) / 256, 256, 0, stream>>>(dec_w0, WtD0, 128, 256);
    k_wsplit<<<(256 * 512) / 256, 256, 0, stream>>>(dec_w1, WtD1, 256, 512);
    k_wsplit<<<(512 * 768) / 256, 256, 0, stream>>>(dec_w2, WtD2, 512, 768);

    k_mfma_rms<256><<<NB / 64, 512, 0, stream>>>(qsum, WtD0, dec_b0, dec_g0, h1, 128);
    k_mfma_rms<512><<<NB / 64, 512, 0, stream>>>(h1, WtD1, dec_b1, dec_g1, h0, 256);

    dim3 g2(NB / 64, 3);
    k_mfma_dec2<<<g2, 512, 0, stream>>>(h0, WtD2, dec_b2, xn, rl, 512);
}